// Round 1
// baseline (3768.131 us; speedup 1.0000x reference)
//
#include <hip/hip_runtime.h>
#include <hip/hip_bf16.h>
#include <math.h>

#define B_ 4
#define T_ 2048
#define M_ 1024
#define H_ 16
#define E_ 8
#define S_ (B_*T_)      // 8192
#define C_ (S_/E_)      // 1024
#define D_ (M_/H_)      // 64
#define F_ (4*M_)       // 4096

__device__ __forceinline__ float gelu_exact(float x) {
    return 0.5f * x * (1.0f + erff(x * 0.70710678118654752440f));
}

// ---------------------------------------------------------------------------
// LayerNorm: one block (256 thr) per row of 1024. Two-pass (matches np var).
// ---------------------------------------------------------------------------
__global__ __launch_bounds__(256) void ln_kernel(const float* __restrict__ x,
                                                 const float* __restrict__ g,
                                                 const float* __restrict__ bta,
                                                 float* __restrict__ out)
{
    const int row = blockIdx.x;
    const int tid = threadIdx.x;
    const float4 v = reinterpret_cast<const float4*>(x + (size_t)row * M_)[tid];
    float s = v.x + v.y + v.z + v.w;
    __shared__ float red[4];
    #pragma unroll
    for (int off = 32; off > 0; off >>= 1) s += __shfl_down(s, off);
    if ((tid & 63) == 0) red[tid >> 6] = s;
    __syncthreads();
    const float mu = (red[0] + red[1] + red[2] + red[3]) * (1.0f / (float)M_);
    __syncthreads();
    float4 d;
    d.x = v.x - mu; d.y = v.y - mu; d.z = v.z - mu; d.w = v.w - mu;
    float q = d.x*d.x + d.y*d.y + d.z*d.z + d.w*d.w;
    #pragma unroll
    for (int off = 32; off > 0; off >>= 1) q += __shfl_down(q, off);
    if ((tid & 63) == 0) red[tid >> 6] = q;
    __syncthreads();
    const float var  = (red[0] + red[1] + red[2] + red[3]) * (1.0f / (float)M_);
    const float rstd = 1.0f / sqrtf(var + 1e-5f);
    const float4 gv = reinterpret_cast<const float4*>(g)[tid];
    const float4 bv = reinterpret_cast<const float4*>(bta)[tid];
    float4 o;
    o.x = d.x * rstd * gv.x + bv.x;
    o.y = d.y * rstd * gv.y + bv.y;
    o.z = d.z * rstd * gv.z + bv.z;
    o.w = d.w * rstd * gv.w + bv.w;
    reinterpret_cast<float4*>(out + (size_t)row * M_)[tid] = o;
}

// ---------------------------------------------------------------------------
// f32 GEMM: C[m][n] = sum_k A[m][k] * B(k,n)  (+ epilogue)
//   BT=true : B stored [N][K] (weight.T convention, rows K-contiguous)
//   BT=false: B stored [K][N]
// 128x128 tile, BK=8, 256 threads, 8x8 microtile (split-block mapping:
// rows {4ty+i, 64+4ty+i}, cols {4tx+j, 64+4tx+j} -> stride-4 b128 LDS reads,
// 2-way bank aliasing = free).
// EPI: 0 = +bias store; 1 = +bias +residual; 2 = +bias +exact GELU;
//      3 = MoE combine: s=token_at[row]; if kept: Cout[s] += gate[s]*(acc+bias)
// blockIdx.z = expert index; str* are per-expert element strides.
// ---------------------------------------------------------------------------
template<bool BT, int EPI>
__global__ __launch_bounds__(256) void gemm_f32(
    const float* __restrict__ A, const float* __restrict__ Bp,
    const float* __restrict__ bias, const float* __restrict__ res,
    const int* __restrict__ token_at, const float* __restrict__ gate_val,
    float* __restrict__ Cc, int N, int K,
    long strA, long strB, long strBias, long strC)
{
    const int ez = blockIdx.z;
    A    += (size_t)ez * (size_t)strA;
    Bp   += (size_t)ez * (size_t)strB;
    bias += (size_t)ez * (size_t)strBias;
    Cc   += (size_t)ez * (size_t)strC;
    if (EPI == 3) token_at += ez * C_;

    __shared__ float As[8][128];
    __shared__ float Bs[8][128];

    const int tid = threadIdx.x;
    const int tx = tid & 15, ty = tid >> 4;
    const int m0 = blockIdx.y * 128, n0 = blockIdx.x * 128;

    const int sar = tid >> 1;          // 0..127 (row for A / row-of-N for BT)
    const int sak = (tid & 1) * 4;     // 0 or 4
    const int sbk = tid >> 5;          // 0..7   (BT=false)
    const int sbn = (tid & 31) * 4;    // 0..124

    float acc[8][8] = {};

    for (int k0 = 0; k0 < K; k0 += 8) {
        const float4 av = *reinterpret_cast<const float4*>(&A[(size_t)(m0 + sar) * K + (k0 + sak)]);
        float4 bv;
        if (BT) bv = *reinterpret_cast<const float4*>(&Bp[(size_t)(n0 + sar) * K + (k0 + sak)]);
        else    bv = *reinterpret_cast<const float4*>(&Bp[(size_t)(k0 + sbk) * N + (n0 + sbn)]);
        __syncthreads();
        As[sak+0][sar] = av.x; As[sak+1][sar] = av.y;
        As[sak+2][sar] = av.z; As[sak+3][sar] = av.w;
        if (BT) {
            Bs[sak+0][sar] = bv.x; Bs[sak+1][sar] = bv.y;
            Bs[sak+2][sar] = bv.z; Bs[sak+3][sar] = bv.w;
        } else {
            *reinterpret_cast<float4*>(&Bs[sbk][sbn]) = bv;
        }
        __syncthreads();
        #pragma unroll
        for (int k = 0; k < 8; ++k) {
            const float4 a0 = *reinterpret_cast<const float4*>(&As[k][4*ty]);
            const float4 a1 = *reinterpret_cast<const float4*>(&As[k][64 + 4*ty]);
            const float4 b0 = *reinterpret_cast<const float4*>(&Bs[k][4*tx]);
            const float4 b1 = *reinterpret_cast<const float4*>(&Bs[k][64 + 4*tx]);
            const float a[8] = {a0.x,a0.y,a0.z,a0.w,a1.x,a1.y,a1.z,a1.w};
            const float b[8] = {b0.x,b0.y,b0.z,b0.w,b1.x,b1.y,b1.z,b1.w};
            #pragma unroll
            for (int i = 0; i < 8; ++i) {
                #pragma unroll
                for (int j = 0; j < 8; ++j)
                    acc[i][j] = fmaf(a[i], b[j], acc[i][j]);
            }
        }
    }

    const int c0 = n0 + 4*tx;
    const int c1 = n0 + 64 + 4*tx;
    const float4 bb0 = *reinterpret_cast<const float4*>(&bias[c0]);
    const float4 bb1 = *reinterpret_cast<const float4*>(&bias[c1]);
    #pragma unroll
    for (int ih = 0; ih < 2; ++ih) {
        #pragma unroll
        for (int i = 0; i < 4; ++i) {
            const int r  = m0 + ih*64 + 4*ty + i;
            const int ri = ih*4 + i;
            float4 v0, v1;
            v0.x = acc[ri][0] + bb0.x; v0.y = acc[ri][1] + bb0.y;
            v0.z = acc[ri][2] + bb0.z; v0.w = acc[ri][3] + bb0.w;
            v1.x = acc[ri][4] + bb1.x; v1.y = acc[ri][5] + bb1.y;
            v1.z = acc[ri][6] + bb1.z; v1.w = acc[ri][7] + bb1.w;
            if (EPI == 0) {
                *reinterpret_cast<float4*>(&Cc[(size_t)r * N + c0]) = v0;
                *reinterpret_cast<float4*>(&Cc[(size_t)r * N + c1]) = v1;
            } else if (EPI == 1) {
                const float4 r0 = *reinterpret_cast<const float4*>(&res[(size_t)r * N + c0]);
                const float4 r1 = *reinterpret_cast<const float4*>(&res[(size_t)r * N + c1]);
                v0.x += r0.x; v0.y += r0.y; v0.z += r0.z; v0.w += r0.w;
                v1.x += r1.x; v1.y += r1.y; v1.z += r1.z; v1.w += r1.w;
                *reinterpret_cast<float4*>(&Cc[(size_t)r * N + c0]) = v0;
                *reinterpret_cast<float4*>(&Cc[(size_t)r * N + c1]) = v1;
            } else if (EPI == 2) {
                v0.x = gelu_exact(v0.x); v0.y = gelu_exact(v0.y);
                v0.z = gelu_exact(v0.z); v0.w = gelu_exact(v0.w);
                v1.x = gelu_exact(v1.x); v1.y = gelu_exact(v1.y);
                v1.z = gelu_exact(v1.z); v1.w = gelu_exact(v1.w);
                *reinterpret_cast<float4*>(&Cc[(size_t)r * N + c0]) = v0;
                *reinterpret_cast<float4*>(&Cc[(size_t)r * N + c1]) = v1;
            } else {
                const int s = token_at[r];
                if (s >= 0) {
                    const float gvl = gate_val[s];
                    float4 o0 = *reinterpret_cast<float4*>(&Cc[(size_t)s * N + c0]);
                    float4 o1 = *reinterpret_cast<float4*>(&Cc[(size_t)s * N + c1]);
                    o0.x += gvl * v0.x; o0.y += gvl * v0.y;
                    o0.z += gvl * v0.z; o0.w += gvl * v0.w;
                    o1.x += gvl * v1.x; o1.y += gvl * v1.y;
                    o1.z += gvl * v1.z; o1.w += gvl * v1.w;
                    *reinterpret_cast<float4*>(&Cc[(size_t)s * N + c0]) = o0;
                    *reinterpret_cast<float4*>(&Cc[(size_t)s * N + c1]) = o1;
                }
            }
        }
    }
}

// ---------------------------------------------------------------------------
// f32 flash attention, causal. Block = 256 thr handles one (b, h, 64-row
// Q-tile). QsT/KsT stored transposed [d][r] so both GEMM operands are
// contiguous float4 LDS reads. P^T reuses the K buffer. Online softmax.
// ---------------------------------------------------------------------------
__global__ __launch_bounds__(256) void attn_kernel(const float* __restrict__ qkv,
                                                   float* __restrict__ o)
{
    const int qt = blockIdx.x;
    const int h  = blockIdx.y;
    const int b  = blockIdx.z;
    const int q0 = qt * 64;

    __shared__ float QsT[64][68];   // Q^T [d][r]
    __shared__ float KPs[64][68];   // K^T [d][c] during S; P^T [c][r] during PV
    __shared__ float Vs [64][68];   // V   [c][d]

    const int tid = threadIdx.x;
    const int tx = tid & 15, ty = tid >> 4;
    const size_t rowbase = (size_t)b * T_;

    {
        const int rr0 = tid >> 4;
        const int d0  = (tid & 15) * 4;
        #pragma unroll
        for (int rr = 0; rr < 4; ++rr) {
            const int r = rr0 + rr * 16;
            const float4 v = *reinterpret_cast<const float4*>(
                &qkv[(rowbase + q0 + r) * (3*M_) + h*D_ + d0]);
            QsT[d0+0][r] = v.x; QsT[d0+1][r] = v.y;
            QsT[d0+2][r] = v.z; QsT[d0+3][r] = v.w;
        }
    }

    float oacc[4][4] = {};
    float mrow[4] = {-__builtin_inff(), -__builtin_inff(), -__builtin_inff(), -__builtin_inff()};
    float lrow[4] = {};

    for (int kt = 0; kt <= qt; ++kt) {
        __syncthreads();
        {
            const int cc0 = tid >> 4;
            const int d0  = (tid & 15) * 4;
            #pragma unroll
            for (int rr = 0; rr < 4; ++rr) {
                const int c = cc0 + rr * 16;
                const size_t rb = (rowbase + kt*64 + c) * (3*M_) + h*D_ + d0;
                const float4 kv = *reinterpret_cast<const float4*>(&qkv[rb + M_]);
                KPs[d0+0][c] = kv.x; KPs[d0+1][c] = kv.y;
                KPs[d0+2][c] = kv.z; KPs[d0+3][c] = kv.w;
                const float4 vv = *reinterpret_cast<const float4*>(&qkv[rb + 2*M_]);
                *reinterpret_cast<float4*>(&Vs[c][d0]) = vv;
            }
        }
        __syncthreads();

        float sreg[4][4] = {};
        #pragma unroll 8
        for (int d = 0; d < 64; ++d) {
            const float4 a  = *reinterpret_cast<const float4*>(&QsT[d][4*ty]);
            const float4 k4 = *reinterpret_cast<const float4*>(&KPs[d][4*tx]);
            const float aa[4] = {a.x, a.y, a.z, a.w};
            const float kk[4] = {k4.x, k4.y, k4.z, k4.w};
            #pragma unroll
            for (int i = 0; i < 4; ++i) {
                #pragma unroll
                for (int j = 0; j < 4; ++j)
                    sreg[i][j] = fmaf(aa[i], kk[j], sreg[i][j]);
            }
        }
        #pragma unroll
        for (int i = 0; i < 4; ++i) {
            #pragma unroll
            for (int j = 0; j < 4; ++j)
                sreg[i][j] *= 0.125f;
        }
        if (kt == qt) {
            #pragma unroll
            for (int i = 0; i < 4; ++i) {
                #pragma unroll
                for (int j = 0; j < 4; ++j)
                    if (4*tx + j > 4*ty + i) sreg[i][j] = -__builtin_inff();
            }
        }

        float tmax[4];
        #pragma unroll
        for (int i = 0; i < 4; ++i)
            tmax[i] = fmaxf(fmaxf(sreg[i][0], sreg[i][1]), fmaxf(sreg[i][2], sreg[i][3]));
        #pragma unroll
        for (int off = 1; off < 16; off <<= 1) {
            #pragma unroll
            for (int i = 0; i < 4; ++i)
                tmax[i] = fmaxf(tmax[i], __shfl_xor(tmax[i], off, 16));
        }
        float mnew[4], corr[4];
        #pragma unroll
        for (int i = 0; i < 4; ++i) {
            mnew[i] = fmaxf(mrow[i], tmax[i]);
            corr[i] = expf(mrow[i] - mnew[i]);   // -inf on first tile -> 0
        }
        float p[4][4];
        float rsum[4] = {};
        #pragma unroll
        for (int i = 0; i < 4; ++i) {
            #pragma unroll
            for (int j = 0; j < 4; ++j) {
                p[i][j] = expf(sreg[i][j] - mnew[i]);   // masked -inf -> 0
                rsum[i] += p[i][j];
            }
        }
        #pragma unroll
        for (int off = 1; off < 16; off <<= 1) {
            #pragma unroll
            for (int i = 0; i < 4; ++i)
                rsum[i] += __shfl_xor(rsum[i], off, 16);
        }
        #pragma unroll
        for (int i = 0; i < 4; ++i) {
            lrow[i] = lrow[i] * corr[i] + rsum[i];
            mrow[i] = mnew[i];
        }
        #pragma unroll
        for (int i = 0; i < 4; ++i) {
            #pragma unroll
            for (int j = 0; j < 4; ++j)
                oacc[i][j] *= corr[i];
        }
        __syncthreads();              // everyone done reading K from KPs
        #pragma unroll
        for (int i = 0; i < 4; ++i) {
            #pragma unroll
            for (int j = 0; j < 4; ++j)
                KPs[4*tx + j][4*ty + i] = p[i][j];   // P^T
        }
        __syncthreads();
        #pragma unroll 8
        for (int c = 0; c < 64; ++c) {
            const float4 a  = *reinterpret_cast<const float4*>(&KPs[c][4*ty]);
            const float4 vv = *reinterpret_cast<const float4*>(&Vs[c][4*tx]);
            const float aa[4] = {a.x, a.y, a.z, a.w};
            const float vj[4] = {vv.x, vv.y, vv.z, vv.w};
            #pragma unroll
            for (int i = 0; i < 4; ++i) {
                #pragma unroll
                for (int j = 0; j < 4; ++j)
                    oacc[i][j] = fmaf(aa[i], vj[j], oacc[i][j]);
            }
        }
    }

    #pragma unroll
    for (int i = 0; i < 4; ++i) {
        const float inv = 1.0f / lrow[i];
        float4 ov;
        ov.x = oacc[i][0] * inv; ov.y = oacc[i][1] * inv;
        ov.z = oacc[i][2] * inv; ov.w = oacc[i][3] * inv;
        *reinterpret_cast<float4*>(&o[(rowbase + q0 + 4*ty + i) * M_ + h*D_ + 4*tx]) = ov;
    }
}

// ---------------------------------------------------------------------------
// Router: logits = h2[s] @ wg, softmax top-1 (first-max-wins, matches argmax).
// One block per token; 32 lanes per expert.
// ---------------------------------------------------------------------------
__global__ __launch_bounds__(256) void gate_kernel(const float* __restrict__ h2,
                                                   const float* __restrict__ wg,
                                                   int* __restrict__ gidx,
                                                   float* __restrict__ gtop)
{
    const int s = blockIdx.x;
    const int e = threadIdx.x >> 5;
    const int l = threadIdx.x & 31;
    const float* row = h2 + (size_t)s * M_;
    float acc = 0.0f;
    for (int m = l; m < M_; m += 32) acc = fmaf(row[m], wg[m * E_ + e], acc);
    #pragma unroll
    for (int off = 16; off > 0; off >>= 1) acc += __shfl_down(acc, off, 32);
    __shared__ float lg[E_];
    if (l == 0) lg[e] = acc;
    __syncthreads();
    if (threadIdx.x == 0) {
        float mx = lg[0]; int bi = 0;
        #pragma unroll
        for (int i = 1; i < E_; ++i) { if (lg[i] > mx) { mx = lg[i]; bi = i; } }
        float den = 0.0f;
        #pragma unroll
        for (int i = 0; i < E_; ++i) den += expf(lg[i] - mx);
        gidx[s] = bi;
        gtop[s] = 1.0f / den;     // softmax value of the top expert
    }
}

// ---------------------------------------------------------------------------
// Exact deepspeed-style dispatch bookkeeping, token order preserved.
// Single block of 1024 threads, 8 tokens each; hierarchical cumsum per expert.
// Produces gate_val (0 for dropped) and inverse map token_at[e*C + pos] = s.
// ---------------------------------------------------------------------------
__global__ __launch_bounds__(1024) void scan_kernel(const int* __restrict__ gidx,
                                                    const float* __restrict__ gtop,
                                                    float* __restrict__ gate_val,
                                                    int* __restrict__ token_at)
{
    __shared__ int hist[1024][E_];
    const int tid = threadIdx.x;
    for (int i = tid; i < E_ * C_; i += 1024) token_at[i] = -1;
    int my[8];
    #pragma unroll
    for (int t = 0; t < 8; ++t) my[t] = gidx[tid * 8 + t];
    #pragma unroll
    for (int e = 0; e < E_; ++e) {
        int c = 0;
        #pragma unroll
        for (int t = 0; t < 8; ++t) c += (my[t] == e) ? 1 : 0;
        hist[tid][e] = c;
    }
    __syncthreads();
    if (tid < E_) {                      // serial exclusive scan per expert
        int run = 0;
        for (int t = 0; t < 1024; ++t) {
            const int v = hist[t][tid];
            hist[t][tid] = run;
            run += v;
        }
    }
    __syncthreads();
    #pragma unroll
    for (int t = 0; t < 8; ++t) {
        const int s = tid * 8 + t;
        const int e = my[t];
        const int p = hist[tid][e];      // position in expert queue
        hist[tid][e] = p + 1;
        const bool keep = (p < C_);
        gate_val[s] = keep ? gtop[s] : 0.0f;
        if (keep) token_at[e * C_ + p] = s;
    }
}

// Gather-based dispatch: disp[e][c][:] = kept ? h2[token] : 0. No atomics.
__global__ __launch_bounds__(256) void dispatch_kernel(const float* __restrict__ h2,
                                                       const int* __restrict__ token_at,
                                                       float* __restrict__ disp)
{
    const int ec = blockIdx.x;
    const int s = token_at[ec];
    float4* dst = reinterpret_cast<float4*>(disp + (size_t)ec * M_);
    if (s >= 0)
        dst[threadIdx.x] = reinterpret_cast<const float4*>(h2 + (size_t)s * M_)[threadIdx.x];
    else
        dst[threadIdx.x] = make_float4(0.f, 0.f, 0.f, 0.f);
}

// ---------------------------------------------------------------------------
extern "C" void kernel_launch(void* const* d_in, const int* in_sizes, int n_in,
                              void* d_out, int out_size, void* d_ws, size_t ws_size,
                              hipStream_t stream)
{
    const float* x    = (const float*)d_in[0];
    const float* ln1g = (const float*)d_in[1];
    const float* ln1b = (const float*)d_in[2];
    const float* Wqkv = (const float*)d_in[3];
    const float* bqkv = (const float*)d_in[4];
    const float* Wout = (const float*)d_in[5];
    const float* bout = (const float*)d_in[6];
    const float* ln2g = (const float*)d_in[7];
    const float* ln2b = (const float*)d_in[8];
    const float* wg   = (const float*)d_in[9];
    const float* w1   = (const float*)d_in[10];
    const float* b1   = (const float*)d_in[11];
    const float* w2   = (const float*)d_in[12];
    const float* b2   = (const float*)d_in[13];
    float* out = (float*)d_out;

    // Workspace layout (floats). Total ~202 MB.
    float* buf_h    = (float*)d_ws;                      // S*M   : ln1 out, then ln2 out
    float* buf_qkv  = buf_h    + (size_t)S_ * M_;        // S*3M  : qkv
    float* buf_o    = buf_qkv  + (size_t)S_ * 3 * M_;    // S*M   : attention out
    float* buf_disp = buf_o    + (size_t)S_ * M_;        // S*M   : dispatched tokens [E][C][M]
    float* buf_h1   = buf_qkv;                           // E*C*F == S*4M: reuses dead qkv+o region
    float* buf_gtop = buf_disp + (size_t)S_ * M_;        // S
    float* buf_gv   = buf_gtop + S_;                     // S
    int*   buf_idx  = (int*)(buf_gv + S_);               // S
    int*   buf_ta   = buf_idx + S_;                      // E*C == S

    // --- attention sub-block (all f32: feeds the top-1 router) ---
    ln_kernel<<<S_, 256, 0, stream>>>(x, ln1g, ln1b, buf_h);
    gemm_f32<true, 0><<<dim3(3*M_/128, S_/128, 1), 256, 0, stream>>>(
        buf_h, Wqkv, bqkv, nullptr, nullptr, nullptr, buf_qkv, 3*M_, M_, 0, 0, 0, 0);
    attn_kernel<<<dim3(T_/64, H_, B_), 256, 0, stream>>>(buf_qkv, buf_o);
    gemm_f32<true, 1><<<dim3(M_/128, S_/128, 1), 256, 0, stream>>>(
        buf_o, Wout, bout, x, nullptr, nullptr, out, M_, M_, 0, 0, 0, 0);

    // --- MoE sub-block ---
    ln_kernel<<<S_, 256, 0, stream>>>(out, ln2g, ln2b, buf_h);
    gate_kernel<<<S_, 256, 0, stream>>>(buf_h, wg, buf_idx, buf_gtop);
    scan_kernel<<<1, 1024, 0, stream>>>(buf_idx, buf_gtop, buf_gv, buf_ta);
    dispatch_kernel<<<E_*C_, 256, 0, stream>>>(buf_h, buf_ta, buf_disp);
    gemm_f32<false, 2><<<dim3(F_/128, C_/128, E_), 256, 0, stream>>>(
        buf_disp, w1, b1, nullptr, nullptr, nullptr, buf_h1, F_, M_,
        (long)C_*M_, (long)M_*F_, (long)F_, (long)C_*F_);
    gemm_f32<false, 3><<<dim3(M_/128, C_/128, E_), 256, 0, stream>>>(
        buf_h1, w2, b2, nullptr, buf_ta, buf_gv, out, M_, F_,
        (long)C_*F_, (long)F_*M_, (long)M_, 0);
}

// Round 2
// 2355.251 us; speedup vs baseline: 1.5999x; 1.5999x over previous
//
#include <hip/hip_runtime.h>
#include <hip/hip_bf16.h>
#include <math.h>

#define B_ 4
#define T_ 2048
#define M_ 1024
#define H_ 16
#define E_ 8
#define S_ (B_*T_)      // 8192
#define C_ (S_/E_)      // 1024
#define D_ (M_/H_)      // 64
#define F_ (4*M_)       // 4096

typedef unsigned short ushort_t;
typedef __attribute__((ext_vector_type(8))) short bf16x8;
typedef __attribute__((ext_vector_type(4))) float f32x4;

__device__ __forceinline__ float gelu_exact(float x) {
    return 0.5f * x * (1.0f + erff(x * 0.70710678118654752440f));
}

__device__ __forceinline__ unsigned short f2bf(float f) {
    unsigned int u = __float_as_uint(f);
    u = (u + 0x7FFFu + ((u >> 16) & 1u)) >> 16;   // RNE
    return (unsigned short)u;
}

__device__ __forceinline__ void gload_lds16(const void* g, void* l) {
    __builtin_amdgcn_global_load_lds(
        (const __attribute__((address_space(1))) unsigned int*)g,
        (__attribute__((address_space(3))) unsigned int*)l,
        16, 0, 0);
}

// ---------------------------------------------------------------------------
// LayerNorm: one block (256 thr) per row of 1024.
// ---------------------------------------------------------------------------
__global__ __launch_bounds__(256) void ln_kernel(const float* __restrict__ x,
                                                 const float* __restrict__ g,
                                                 const float* __restrict__ bta,
                                                 float* __restrict__ out)
{
    const int row = blockIdx.x;
    const int tid = threadIdx.x;
    const float4 v = reinterpret_cast<const float4*>(x + (size_t)row * M_)[tid];
    float s = v.x + v.y + v.z + v.w;
    __shared__ float red[4];
    #pragma unroll
    for (int off = 32; off > 0; off >>= 1) s += __shfl_down(s, off);
    if ((tid & 63) == 0) red[tid >> 6] = s;
    __syncthreads();
    const float mu = (red[0] + red[1] + red[2] + red[3]) * (1.0f / (float)M_);
    __syncthreads();
    float4 d;
    d.x = v.x - mu; d.y = v.y - mu; d.z = v.z - mu; d.w = v.w - mu;
    float q = d.x*d.x + d.y*d.y + d.z*d.z + d.w*d.w;
    #pragma unroll
    for (int off = 32; off > 0; off >>= 1) q += __shfl_down(q, off);
    if ((tid & 63) == 0) red[tid >> 6] = q;
    __syncthreads();
    const float var  = (red[0] + red[1] + red[2] + red[3]) * (1.0f / (float)M_);
    const float rstd = 1.0f / sqrtf(var + 1e-5f);
    const float4 gv = reinterpret_cast<const float4*>(g)[tid];
    const float4 bv = reinterpret_cast<const float4*>(bta)[tid];
    float4 o;
    o.x = d.x * rstd * gv.x + bv.x;
    o.y = d.y * rstd * gv.y + bv.y;
    o.z = d.z * rstd * gv.z + bv.z;
    o.w = d.w * rstd * gv.w + bv.w;
    reinterpret_cast<float4*>(out + (size_t)row * M_)[tid] = o;
}

// ---------------------------------------------------------------------------
// f32 GEMM (pre-router path; must stay f32-grade).
// EPI: 0 = +bias store; 1 = +bias +residual.
// ---------------------------------------------------------------------------
template<bool BT, int EPI>
__global__ __launch_bounds__(256) void gemm_f32(
    const float* __restrict__ A, const float* __restrict__ Bp,
    const float* __restrict__ bias, const float* __restrict__ res,
    float* __restrict__ Cc, int N, int K)
{
    __shared__ float As[8][128];
    __shared__ float Bs[8][128];

    const int tid = threadIdx.x;
    const int tx = tid & 15, ty = tid >> 4;
    const int m0 = blockIdx.y * 128, n0 = blockIdx.x * 128;

    const int sar = tid >> 1;
    const int sak = (tid & 1) * 4;
    const int sbk = tid >> 5;
    const int sbn = (tid & 31) * 4;

    float acc[8][8] = {};

    for (int k0 = 0; k0 < K; k0 += 8) {
        const float4 av = *reinterpret_cast<const float4*>(&A[(size_t)(m0 + sar) * K + (k0 + sak)]);
        float4 bv;
        if (BT) bv = *reinterpret_cast<const float4*>(&Bp[(size_t)(n0 + sar) * K + (k0 + sak)]);
        else    bv = *reinterpret_cast<const float4*>(&Bp[(size_t)(k0 + sbk) * N + (n0 + sbn)]);
        __syncthreads();
        As[sak+0][sar] = av.x; As[sak+1][sar] = av.y;
        As[sak+2][sar] = av.z; As[sak+3][sar] = av.w;
        if (BT) {
            Bs[sak+0][sar] = bv.x; Bs[sak+1][sar] = bv.y;
            Bs[sak+2][sar] = bv.z; Bs[sak+3][sar] = bv.w;
        } else {
            *reinterpret_cast<float4*>(&Bs[sbk][sbn]) = bv;
        }
        __syncthreads();
        #pragma unroll
        for (int k = 0; k < 8; ++k) {
            const float4 a0 = *reinterpret_cast<const float4*>(&As[k][4*ty]);
            const float4 a1 = *reinterpret_cast<const float4*>(&As[k][64 + 4*ty]);
            const float4 b0 = *reinterpret_cast<const float4*>(&Bs[k][4*tx]);
            const float4 b1 = *reinterpret_cast<const float4*>(&Bs[k][64 + 4*tx]);
            const float a[8] = {a0.x,a0.y,a0.z,a0.w,a1.x,a1.y,a1.z,a1.w};
            const float b[8] = {b0.x,b0.y,b0.z,b0.w,b1.x,b1.y,b1.z,b1.w};
            #pragma unroll
            for (int i = 0; i < 8; ++i) {
                #pragma unroll
                for (int j = 0; j < 8; ++j)
                    acc[i][j] = fmaf(a[i], b[j], acc[i][j]);
            }
        }
    }

    const int c0 = n0 + 4*tx;
    const int c1 = n0 + 64 + 4*tx;
    const float4 bb0 = *reinterpret_cast<const float4*>(&bias[c0]);
    const float4 bb1 = *reinterpret_cast<const float4*>(&bias[c1]);
    #pragma unroll
    for (int ih = 0; ih < 2; ++ih) {
        #pragma unroll
        for (int i = 0; i < 4; ++i) {
            const int r  = m0 + ih*64 + 4*ty + i;
            const int ri = ih*4 + i;
            float4 v0, v1;
            v0.x = acc[ri][0] + bb0.x; v0.y = acc[ri][1] + bb0.y;
            v0.z = acc[ri][2] + bb0.z; v0.w = acc[ri][3] + bb0.w;
            v1.x = acc[ri][4] + bb1.x; v1.y = acc[ri][5] + bb1.y;
            v1.z = acc[ri][6] + bb1.z; v1.w = acc[ri][7] + bb1.w;
            if (EPI == 1) {
                const float4 r0 = *reinterpret_cast<const float4*>(&res[(size_t)r * N + c0]);
                const float4 r1 = *reinterpret_cast<const float4*>(&res[(size_t)r * N + c1]);
                v0.x += r0.x; v0.y += r0.y; v0.z += r0.z; v0.w += r0.w;
                v1.x += r1.x; v1.y += r1.y; v1.z += r1.z; v1.w += r1.w;
            }
            *reinterpret_cast<float4*>(&Cc[(size_t)r * N + c0]) = v0;
            *reinterpret_cast<float4*>(&Cc[(size_t)r * N + c1]) = v1;
        }
    }
}

// ---------------------------------------------------------------------------
// f32 flash attention, causal (unchanged from round 1).
// ---------------------------------------------------------------------------
__global__ __launch_bounds__(256) void attn_kernel(const float* __restrict__ qkv,
                                                   float* __restrict__ o)
{
    const int qt = blockIdx.x;
    const int h  = blockIdx.y;
    const int b  = blockIdx.z;
    const int q0 = qt * 64;

    __shared__ float QsT[64][68];
    __shared__ float KPs[64][68];
    __shared__ float Vs [64][68];

    const int tid = threadIdx.x;
    const int tx = tid & 15, ty = tid >> 4;
    const size_t rowbase = (size_t)b * T_;

    {
        const int rr0 = tid >> 4;
        const int d0  = (tid & 15) * 4;
        #pragma unroll
        for (int rr = 0; rr < 4; ++rr) {
            const int r = rr0 + rr * 16;
            const float4 v = *reinterpret_cast<const float4*>(
                &qkv[(rowbase + q0 + r) * (3*M_) + h*D_ + d0]);
            QsT[d0+0][r] = v.x; QsT[d0+1][r] = v.y;
            QsT[d0+2][r] = v.z; QsT[d0+3][r] = v.w;
        }
    }

    float oacc[4][4] = {};
    float mrow[4] = {-__builtin_inff(), -__builtin_inff(), -__builtin_inff(), -__builtin_inff()};
    float lrow[4] = {};

    for (int kt = 0; kt <= qt; ++kt) {
        __syncthreads();
        {
            const int cc0 = tid >> 4;
            const int d0  = (tid & 15) * 4;
            #pragma unroll
            for (int rr = 0; rr < 4; ++rr) {
                const int c = cc0 + rr * 16;
                const size_t rb = (rowbase + kt*64 + c) * (3*M_) + h*D_ + d0;
                const float4 kv = *reinterpret_cast<const float4*>(&qkv[rb + M_]);
                KPs[d0+0][c] = kv.x; KPs[d0+1][c] = kv.y;
                KPs[d0+2][c] = kv.z; KPs[d0+3][c] = kv.w;
                const float4 vv = *reinterpret_cast<const float4*>(&qkv[rb + 2*M_]);
                *reinterpret_cast<float4*>(&Vs[c][d0]) = vv;
            }
        }
        __syncthreads();

        float sreg[4][4] = {};
        #pragma unroll 8
        for (int d = 0; d < 64; ++d) {
            const float4 a  = *reinterpret_cast<const float4*>(&QsT[d][4*ty]);
            const float4 k4 = *reinterpret_cast<const float4*>(&KPs[d][4*tx]);
            const float aa[4] = {a.x, a.y, a.z, a.w};
            const float kk[4] = {k4.x, k4.y, k4.z, k4.w};
            #pragma unroll
            for (int i = 0; i < 4; ++i) {
                #pragma unroll
                for (int j = 0; j < 4; ++j)
                    sreg[i][j] = fmaf(aa[i], kk[j], sreg[i][j]);
            }
        }
        #pragma unroll
        for (int i = 0; i < 4; ++i) {
            #pragma unroll
            for (int j = 0; j < 4; ++j)
                sreg[i][j] *= 0.125f;
        }
        if (kt == qt) {
            #pragma unroll
            for (int i = 0; i < 4; ++i) {
                #pragma unroll
                for (int j = 0; j < 4; ++j)
                    if (4*tx + j > 4*ty + i) sreg[i][j] = -__builtin_inff();
            }
        }

        float tmax[4];
        #pragma unroll
        for (int i = 0; i < 4; ++i)
            tmax[i] = fmaxf(fmaxf(sreg[i][0], sreg[i][1]), fmaxf(sreg[i][2], sreg[i][3]));
        #pragma unroll
        for (int off = 1; off < 16; off <<= 1) {
            #pragma unroll
            for (int i = 0; i < 4; ++i)
                tmax[i] = fmaxf(tmax[i], __shfl_xor(tmax[i], off, 16));
        }
        float mnew[4], corr[4];
        #pragma unroll
        for (int i = 0; i < 4; ++i) {
            mnew[i] = fmaxf(mrow[i], tmax[i]);
            corr[i] = expf(mrow[i] - mnew[i]);
        }
        float p[4][4];
        float rsum[4] = {};
        #pragma unroll
        for (int i = 0; i < 4; ++i) {
            #pragma unroll
            for (int j = 0; j < 4; ++j) {
                p[i][j] = expf(sreg[i][j] - mnew[i]);
                rsum[i] += p[i][j];
            }
        }
        #pragma unroll
        for (int off = 1; off < 16; off <<= 1) {
            #pragma unroll
            for (int i = 0; i < 4; ++i)
                rsum[i] += __shfl_xor(rsum[i], off, 16);
        }
        #pragma unroll
        for (int i = 0; i < 4; ++i) {
            lrow[i] = lrow[i] * corr[i] + rsum[i];
            mrow[i] = mnew[i];
        }
        #pragma unroll
        for (int i = 0; i < 4; ++i) {
            #pragma unroll
            for (int j = 0; j < 4; ++j)
                oacc[i][j] *= corr[i];
        }
        __syncthreads();
        #pragma unroll
        for (int i = 0; i < 4; ++i) {
            #pragma unroll
            for (int j = 0; j < 4; ++j)
                KPs[4*tx + j][4*ty + i] = p[i][j];
        }
        __syncthreads();
        #pragma unroll 8
        for (int c = 0; c < 64; ++c) {
            const float4 a  = *reinterpret_cast<const float4*>(&KPs[c][4*ty]);
            const float4 vv = *reinterpret_cast<const float4*>(&Vs[c][4*tx]);
            const float aa[4] = {a.x, a.y, a.z, a.w};
            const float vj[4] = {vv.x, vv.y, vv.z, vv.w};
            #pragma unroll
            for (int i = 0; i < 4; ++i) {
                #pragma unroll
                for (int j = 0; j < 4; ++j)
                    oacc[i][j] = fmaf(aa[i], vj[j], oacc[i][j]);
            }
        }
    }

    #pragma unroll
    for (int i = 0; i < 4; ++i) {
        const float inv = 1.0f / lrow[i];
        float4 ov;
        ov.x = oacc[i][0] * inv; ov.y = oacc[i][1] * inv;
        ov.z = oacc[i][2] * inv; ov.w = oacc[i][3] * inv;
        *reinterpret_cast<float4*>(&o[(rowbase + q0 + 4*ty + i) * M_ + h*D_ + 4*tx]) = ov;
    }
}

// ---------------------------------------------------------------------------
// Router + deepspeed dispatch bookkeeping (exact, f32).
// ---------------------------------------------------------------------------
__global__ __launch_bounds__(256) void gate_kernel(const float* __restrict__ h2,
                                                   const float* __restrict__ wg,
                                                   int* __restrict__ gidx,
                                                   float* __restrict__ gtop)
{
    const int s = blockIdx.x;
    const int e = threadIdx.x >> 5;
    const int l = threadIdx.x & 31;
    const float* row = h2 + (size_t)s * M_;
    float acc = 0.0f;
    for (int m = l; m < M_; m += 32) acc = fmaf(row[m], wg[m * E_ + e], acc);
    #pragma unroll
    for (int off = 16; off > 0; off >>= 1) acc += __shfl_down(acc, off, 32);
    __shared__ float lg[E_];
    if (l == 0) lg[e] = acc;
    __syncthreads();
    if (threadIdx.x == 0) {
        float mx = lg[0]; int bi = 0;
        #pragma unroll
        for (int i = 1; i < E_; ++i) { if (lg[i] > mx) { mx = lg[i]; bi = i; } }
        float den = 0.0f;
        #pragma unroll
        for (int i = 0; i < E_; ++i) den += expf(lg[i] - mx);
        gidx[s] = bi;
        gtop[s] = 1.0f / den;
    }
}

__global__ __launch_bounds__(1024) void scan_kernel(const int* __restrict__ gidx,
                                                    const float* __restrict__ gtop,
                                                    float* __restrict__ gate_val,
                                                    int* __restrict__ token_at)
{
    __shared__ int hist[1024][E_];
    const int tid = threadIdx.x;
    for (int i = tid; i < E_ * C_; i += 1024) token_at[i] = -1;
    int my[8];
    #pragma unroll
    for (int t = 0; t < 8; ++t) my[t] = gidx[tid * 8 + t];
    #pragma unroll
    for (int e = 0; e < E_; ++e) {
        int c = 0;
        #pragma unroll
        for (int t = 0; t < 8; ++t) c += (my[t] == e) ? 1 : 0;
        hist[tid][e] = c;
    }
    __syncthreads();
    if (tid < E_) {
        int run = 0;
        for (int t = 0; t < 1024; ++t) {
            const int v = hist[t][tid];
            hist[t][tid] = run;
            run += v;
        }
    }
    __syncthreads();
    #pragma unroll
    for (int t = 0; t < 8; ++t) {
        const int s = tid * 8 + t;
        const int e = my[t];
        const int p = hist[tid][e];
        hist[tid][e] = p + 1;
        const bool keep = (p < C_);
        gate_val[s] = keep ? gtop[s] : 0.0f;
        if (keep) token_at[e * C_ + p] = s;
    }
}

// Gather-dispatch straight to bf16 [E][C][M].
__global__ __launch_bounds__(256) void dispatch_bf16_kernel(const float* __restrict__ h2,
                                                            const int* __restrict__ token_at,
                                                            ushort_t* __restrict__ disp)
{
    const int ec = blockIdx.x;
    const int s = token_at[ec];
    ushort4* dst = reinterpret_cast<ushort4*>(disp + (size_t)ec * M_);
    if (s >= 0) {
        const float4 v = reinterpret_cast<const float4*>(h2 + (size_t)s * M_)[threadIdx.x];
        dst[threadIdx.x] = make_ushort4(f2bf(v.x), f2bf(v.y), f2bf(v.z), f2bf(v.w));
    } else {
        dst[threadIdx.x] = make_ushort4(0, 0, 0, 0);
    }
}

// Transpose+convert: in[e][R][Cc] f32 -> out[e][Cc][R] bf16.
__global__ __launch_bounds__(256) void transpose_bf16_kernel(const float* __restrict__ in,
                                                             ushort_t* __restrict__ outp,
                                                             int R, int Cc)
{
    __shared__ float tile[32][33];
    const int e = blockIdx.z;
    in   += (size_t)e * R * Cc;
    outp += (size_t)e * R * Cc;
    const int tx = threadIdx.x & 31, ty0 = threadIdx.x >> 5;
    const int c0 = blockIdx.x * 32, r0 = blockIdx.y * 32;
    #pragma unroll
    for (int i = 0; i < 4; ++i)
        tile[ty0 + 8*i][tx] = in[(size_t)(r0 + ty0 + 8*i) * Cc + c0 + tx];
    __syncthreads();
    #pragma unroll
    for (int i = 0; i < 4; ++i)
        outp[(size_t)(c0 + ty0 + 8*i) * R + r0 + tx] = f2bf(tile[tx][ty0 + 8*i]);
}

// ---------------------------------------------------------------------------
// bf16 MFMA GEMM, m97 structure: 128x128 tile, BK=32, 4 waves (2x2 of 64x64),
// 16x16x32 MFMA (4x4 fragments/wave), global_load_lds width-16, linear LDS.
// A [rows][K] bf16 row-major; Bt [N][K] bf16 row-major. f32 accumulate.
// EPI 0: h1 = bf16(gelu(acc + bias))   (per-expert strC)
// EPI 1: out[token_at[r]] += gate * (acc + bias)   (scatter-combine, f32)
// ---------------------------------------------------------------------------
template<int EPI>
__global__ __launch_bounds__(256) void gemm_mfma(
    const ushort_t* __restrict__ A, const ushort_t* __restrict__ Bt,
    const float* __restrict__ bias,
    const int* __restrict__ token_at, const float* __restrict__ gate_val,
    void* __restrict__ Cout, int N, int K,
    long strA, long strB, long strBias, long strC)
{
    const int e = blockIdx.z;
    A    += (size_t)e * (size_t)strA;
    Bt   += (size_t)e * (size_t)strB;
    bias += (size_t)e * (size_t)strBias;

    __shared__ ushort_t As[128 * 32];
    __shared__ ushort_t Bs[128 * 32];

    const int t  = threadIdx.x;
    const int l  = t & 63;
    const int wv = t >> 6;
    const int wm = (wv & 1) * 64, wn = (wv >> 1) * 64;
    const int fr = l & 15, fk = (l >> 4) * 8;      // frag: row=l&15, k=(l>>4)*8..+7
    const int m0 = blockIdx.y * 128, n0 = blockIdx.x * 128;

    // staging: thread t covers row=t>>2, kseg=(t&3)*8 (and +64 rows on issue 2)
    const ushort_t* gA = A + (size_t)(m0 + (t >> 2)) * K + (t & 3) * 8;
    const ushort_t* gB = Bt + (size_t)(n0 + (t >> 2)) * K + (t & 3) * 8;
    ushort_t* lA = As + wv * 512;                  // wave-uniform LDS base
    ushort_t* lB = Bs + wv * 512;

    f32x4 acc[4][4] = {};

    for (int k0 = 0; k0 < K; k0 += 32) {
        __syncthreads();
        gload_lds16(gA + k0, lA);
        gload_lds16(gA + k0 + (size_t)64 * K, lA + 2048);
        gload_lds16(gB + k0, lB);
        gload_lds16(gB + k0 + (size_t)64 * K, lB + 2048);
        __syncthreads();
        bf16x8 af[4], bfr[4];
        #pragma unroll
        for (int i = 0; i < 4; ++i)
            af[i] = *reinterpret_cast<const bf16x8*>(&As[(wm + i*16 + fr) * 32 + fk]);
        #pragma unroll
        for (int i = 0; i < 4; ++i)
            bfr[i] = *reinterpret_cast<const bf16x8*>(&Bs[(wn + i*16 + fr) * 32 + fk]);
        #pragma unroll
        for (int mi = 0; mi < 4; ++mi) {
            #pragma unroll
            for (int ni = 0; ni < 4; ++ni)
                acc[mi][ni] = __builtin_amdgcn_mfma_f32_16x16x32_bf16(
                    af[mi], bfr[ni], acc[mi][ni], 0, 0, 0);
        }
    }

    // C/D layout: col = lane&15, row = (lane>>4)*4 + reg  [m89/m91 verified]
    const int l4 = (l >> 4) * 4;
    if (EPI == 0) {
        ushort_t* Cc = (ushort_t*)Cout + (size_t)e * (size_t)strC;
        #pragma unroll
        for (int ni = 0; ni < 4; ++ni) {
            const int cl = n0 + wn + ni*16 + fr;
            const float bb = bias[cl];
            #pragma unroll
            for (int mi = 0; mi < 4; ++mi) {
                #pragma unroll
                for (int i = 0; i < 4; ++i) {
                    const int r = m0 + wm + mi*16 + l4 + i;
                    Cc[(size_t)r * N + cl] = f2bf(gelu_exact(acc[mi][ni][i] + bb));
                }
            }
        }
    } else {
        float* Co = (float*)Cout;
        const int* ta = token_at + e * C_;
        #pragma unroll
        for (int mi = 0; mi < 4; ++mi) {
            #pragma unroll
            for (int i = 0; i < 4; ++i) {
                const int r = m0 + wm + mi*16 + l4 + i;
                const int s = ta[r];
                if (s >= 0) {
                    const float g = gate_val[s];
                    #pragma unroll
                    for (int ni = 0; ni < 4; ++ni) {
                        const int cl = n0 + wn + ni*16 + fr;
                        Co[(size_t)s * N + cl] += g * (acc[mi][ni][i] + bias[cl]);
                    }
                }
            }
        }
    }
}

// ---------------------------------------------------------------------------
extern "C" void kernel_launch(void* const* d_in, const int* in_sizes, int n_in,
                              void* d_out, int out_size, void* d_ws, size_t ws_size,
                              hipStream_t stream)
{
    const float* x    = (const float*)d_in[0];
    const float* ln1g = (const float*)d_in[1];
    const float* ln1b = (const float*)d_in[2];
    const float* Wqkv = (const float*)d_in[3];
    const float* bqkv = (const float*)d_in[4];
    const float* Wout = (const float*)d_in[5];
    const float* bout = (const float*)d_in[6];
    const float* ln2g = (const float*)d_in[7];
    const float* ln2b = (const float*)d_in[8];
    const float* wg   = (const float*)d_in[9];
    const float* w1   = (const float*)d_in[10];
    const float* b1   = (const float*)d_in[11];
    const float* w2   = (const float*)d_in[12];
    const float* b2   = (const float*)d_in[13];
    float* out = (float*)d_out;

    // Workspace layout (byte offsets in MiB), lifetime-scheduled. Peak ~177 MiB.
    //  [0,32)   buf_h   (ln1 out -> ln2 out; dead after dispatch)
    //  [32,128) buf_qkv (dead after attn)  -> then w1t [32,96) -> then w2t [32,96)
    //  [96,112) disp bf16 (dead qkv upper half)
    //  [128,160) buf_o  (dead after out-proj)
    //  [112,176) h1 bf16 (dead qkv tail + dead buf_o + 16 MiB fresh)
    //  [176,~)  router smalls (live until G2)
    char* ws = (char*)d_ws;
    float*    buf_h   = (float*)ws;
    float*    buf_qkv = (float*)(ws + ((size_t)32  << 20));
    float*    buf_o   = (float*)(ws + ((size_t)128 << 20));
    ushort_t* w1t     = (ushort_t*)(ws + ((size_t)32  << 20));
    ushort_t* w2t     = (ushort_t*)(ws + ((size_t)32  << 20));
    ushort_t* dispb   = (ushort_t*)(ws + ((size_t)96  << 20));
    ushort_t* h1b     = (ushort_t*)(ws + ((size_t)112 << 20));
    float*    buf_gtop= (float*)(ws + ((size_t)176 << 20));
    float*    buf_gv  = buf_gtop + S_;
    int*      buf_idx = (int*)(buf_gv + S_);
    int*      buf_ta  = buf_idx + S_;

    // --- pre-router path (f32) ---
    ln_kernel<<<S_, 256, 0, stream>>>(x, ln1g, ln1b, buf_h);
    gemm_f32<true, 0><<<dim3(3*M_/128, S_/128, 1), 256, 0, stream>>>(
        buf_h, Wqkv, bqkv, nullptr, buf_qkv, 3*M_, M_);
    attn_kernel<<<dim3(T_/64, H_, B_), 256, 0, stream>>>(buf_qkv, buf_o);
    gemm_f32<true, 1><<<dim3(M_/128, S_/128, 1), 256, 0, stream>>>(
        buf_o, Wout, bout, x, out, M_, M_);
    ln_kernel<<<S_, 256, 0, stream>>>(out, ln2g, ln2b, buf_h);
    gate_kernel<<<S_, 256, 0, stream>>>(buf_h, wg, buf_idx, buf_gtop);
    scan_kernel<<<1, 1024, 0, stream>>>(buf_idx, buf_gtop, buf_gv, buf_ta);
    dispatch_bf16_kernel<<<E_*C_, 256, 0, stream>>>(buf_h, buf_ta, dispb);

    // --- MoE FFN (bf16 MFMA) ---
    // w1 [E][M][F] -> w1t [E][F][M]   (qkv region is dead now)
    transpose_bf16_kernel<<<dim3(F_/32, M_/32, E_), 256, 0, stream>>>(w1, w1t, M_, F_);
    gemm_mfma<0><<<dim3(F_/128, C_/128, E_), 256, 0, stream>>>(
        dispb, w1t, b1, nullptr, nullptr, h1b, F_, M_,
        (long)C_*M_, (long)F_*M_, (long)F_, (long)C_*F_);
    // w2 [E][F][M] -> w2t [E][M][F]   (w1t region is dead now)
    transpose_bf16_kernel<<<dim3(M_/32, F_/32, E_), 256, 0, stream>>>(w2, w2t, F_, M_);
    gemm_mfma<1><<<dim3(M_/128, C_/128, E_), 256, 0, stream>>>(
        h1b, w2t, b2, buf_ta, buf_gv, out, M_, F_,
        (long)C_*F_, (long)M_*F_, (long)M_, 0);
}

// Round 4
// 1847.074 us; speedup vs baseline: 2.0401x; 1.2751x over previous
//
#include <hip/hip_runtime.h>
#include <hip/hip_bf16.h>
#include <math.h>

#define B_ 4
#define T_ 2048
#define M_ 1024
#define H_ 16
#define E_ 8
#define S_ (B_*T_)      // 8192
#define C_ (S_/E_)      // 1024
#define D_ (M_/H_)      // 64
#define F_ (4*M_)       // 4096

typedef unsigned short ushort_t;
typedef __attribute__((ext_vector_type(8))) short bf16x8;
typedef __attribute__((ext_vector_type(4))) float f32x4;

__device__ __forceinline__ float gelu_exact(float x) {
    return 0.5f * x * (1.0f + erff(x * 0.70710678118654752440f));
}

__device__ __forceinline__ unsigned short f2bf(float f) {
    unsigned int u = __float_as_uint(f);
    u = (u + 0x7FFFu + ((u >> 16) & 1u)) >> 16;   // RNE
    return (unsigned short)u;
}

__device__ __forceinline__ float bf2f(unsigned short h) {
    return __uint_as_float(((unsigned)h) << 16);
}

__device__ __forceinline__ void gload_lds16(const void* g, void* l) {
    __builtin_amdgcn_global_load_lds(
        (const __attribute__((address_space(1))) unsigned int*)g,
        (__attribute__((address_space(3))) unsigned int*)l,
        16, 0, 0);
}

// RNE split: hi = RNE_bf16(f); lo = RNE_bf16(f - hi) (Sterbenz: f-hi exact in f32).
// hi + lo = f to ~2^-18 rel worst case — bf16x3 product error ~2^-19 rel.
__device__ __forceinline__ void split8(const float4 a, const float4 b,
                                       bf16x8* hi, bf16x8* lo) {
    const float f[8] = {a.x, a.y, a.z, a.w, b.x, b.y, b.z, b.w};
    bf16x8 h, lw;
    #pragma unroll
    for (int j = 0; j < 8; ++j) {
        const unsigned short hb = f2bf(f[j]);
        h[j] = (short)hb;
        lw[j] = (short)f2bf(f[j] - bf2f(hb));
    }
    *hi = h; *lo = lw;
}

__device__ __forceinline__ void lgkm0() {
    asm volatile("s_waitcnt lgkmcnt(0)" ::: "memory");
}

// ---------------------------------------------------------------------------
// LayerNorm: one block (256 thr) per row of 1024.
// ---------------------------------------------------------------------------
__global__ __launch_bounds__(256) void ln_kernel(const float* __restrict__ x,
                                                 const float* __restrict__ g,
                                                 const float* __restrict__ bta,
                                                 float* __restrict__ out)
{
    const int row = blockIdx.x;
    const int tid = threadIdx.x;
    const float4 v = reinterpret_cast<const float4*>(x + (size_t)row * M_)[tid];
    float s = v.x + v.y + v.z + v.w;
    __shared__ float red[4];
    #pragma unroll
    for (int off = 32; off > 0; off >>= 1) s += __shfl_down(s, off);
    if ((tid & 63) == 0) red[tid >> 6] = s;
    __syncthreads();
    const float mu = (red[0] + red[1] + red[2] + red[3]) * (1.0f / (float)M_);
    __syncthreads();
    float4 d;
    d.x = v.x - mu; d.y = v.y - mu; d.z = v.z - mu; d.w = v.w - mu;
    float q = d.x*d.x + d.y*d.y + d.z*d.z + d.w*d.w;
    #pragma unroll
    for (int off = 32; off > 0; off >>= 1) q += __shfl_down(q, off);
    if ((tid & 63) == 0) red[tid >> 6] = q;
    __syncthreads();
    const float var  = (red[0] + red[1] + red[2] + red[3]) * (1.0f / (float)M_);
    const float rstd = 1.0f / sqrtf(var + 1e-5f);
    const float4 gv = reinterpret_cast<const float4*>(g)[tid];
    const float4 bv = reinterpret_cast<const float4*>(bta)[tid];
    float4 o;
    o.x = d.x * rstd * gv.x + bv.x;
    o.y = d.y * rstd * gv.y + bv.y;
    o.z = d.z * rstd * gv.z + bv.z;
    o.w = d.w * rstd * gv.w + bv.w;
    reinterpret_cast<float4*>(out + (size_t)row * M_)[tid] = o;
}

// ---------------------------------------------------------------------------
// f32 GEMM (pre-router path). EPI: 0 = +bias store; 1 = +bias +residual.
// ---------------------------------------------------------------------------
template<bool BT, int EPI>
__global__ __launch_bounds__(256) void gemm_f32(
    const float* __restrict__ A, const float* __restrict__ Bp,
    const float* __restrict__ bias, const float* __restrict__ res,
    float* __restrict__ Cc, int N, int K)
{
    __shared__ float As[8][128];
    __shared__ float Bs[8][128];

    const int tid = threadIdx.x;
    const int tx = tid & 15, ty = tid >> 4;
    const int m0 = blockIdx.y * 128, n0 = blockIdx.x * 128;

    const int sar = tid >> 1;
    const int sak = (tid & 1) * 4;
    const int sbk = tid >> 5;
    const int sbn = (tid & 31) * 4;

    float acc[8][8] = {};

    for (int k0 = 0; k0 < K; k0 += 8) {
        const float4 av = *reinterpret_cast<const float4*>(&A[(size_t)(m0 + sar) * K + (k0 + sak)]);
        float4 bv;
        if (BT) bv = *reinterpret_cast<const float4*>(&Bp[(size_t)(n0 + sar) * K + (k0 + sak)]);
        else    bv = *reinterpret_cast<const float4*>(&Bp[(size_t)(k0 + sbk) * N + (n0 + sbn)]);
        __syncthreads();
        As[sak+0][sar] = av.x; As[sak+1][sar] = av.y;
        As[sak+2][sar] = av.z; As[sak+3][sar] = av.w;
        if (BT) {
            Bs[sak+0][sar] = bv.x; Bs[sak+1][sar] = bv.y;
            Bs[sak+2][sar] = bv.z; Bs[sak+3][sar] = bv.w;
        } else {
            *reinterpret_cast<float4*>(&Bs[sbk][sbn]) = bv;
        }
        __syncthreads();
        #pragma unroll
        for (int k = 0; k < 8; ++k) {
            const float4 a0 = *reinterpret_cast<const float4*>(&As[k][4*ty]);
            const float4 a1 = *reinterpret_cast<const float4*>(&As[k][64 + 4*ty]);
            const float4 b0 = *reinterpret_cast<const float4*>(&Bs[k][4*tx]);
            const float4 b1 = *reinterpret_cast<const float4*>(&Bs[k][64 + 4*tx]);
            const float a[8] = {a0.x,a0.y,a0.z,a0.w,a1.x,a1.y,a1.z,a1.w};
            const float b[8] = {b0.x,b0.y,b0.z,b0.w,b1.x,b1.y,b1.z,b1.w};
            #pragma unroll
            for (int i = 0; i < 8; ++i) {
                #pragma unroll
                for (int j = 0; j < 8; ++j)
                    acc[i][j] = fmaf(a[i], b[j], acc[i][j]);
            }
        }
    }

    const int c0 = n0 + 4*tx;
    const int c1 = n0 + 64 + 4*tx;
    const float4 bb0 = *reinterpret_cast<const float4*>(&bias[c0]);
    const float4 bb1 = *reinterpret_cast<const float4*>(&bias[c1]);
    #pragma unroll
    for (int ih = 0; ih < 2; ++ih) {
        #pragma unroll
        for (int i = 0; i < 4; ++i) {
            const int r  = m0 + ih*64 + 4*ty + i;
            const int ri = ih*4 + i;
            float4 v0, v1;
            v0.x = acc[ri][0] + bb0.x; v0.y = acc[ri][1] + bb0.y;
            v0.z = acc[ri][2] + bb0.z; v0.w = acc[ri][3] + bb0.w;
            v1.x = acc[ri][4] + bb1.x; v1.y = acc[ri][5] + bb1.y;
            v1.z = acc[ri][6] + bb1.z; v1.w = acc[ri][7] + bb1.w;
            if (EPI == 1) {
                const float4 r0 = *reinterpret_cast<const float4*>(&res[(size_t)r * N + c0]);
                const float4 r1 = *reinterpret_cast<const float4*>(&res[(size_t)r * N + c1]);
                v0.x += r0.x; v0.y += r0.y; v0.z += r0.z; v0.w += r0.w;
                v1.x += r1.x; v1.y += r1.y; v1.z += r1.z; v1.w += r1.w;
            }
            *reinterpret_cast<float4*>(&Cc[(size_t)r * N + c0]) = v0;
            *reinterpret_cast<float4*>(&Cc[(size_t)r * N + c1]) = v1;
        }
    }
}

// ---------------------------------------------------------------------------
// bf16x3 MFMA flash attention (f32-grade: feeds the router). RNE hi/lo split.
// Block = 256 thr = 4 waves; wave w owns q-rows [q0+16w, q0+16w+16).
// K : LDS row-major [kv][64], XOR-swizzled ((row&7)<<4), bf16x8 frag reads.
// V : LDS TRANSPOSED [d][72] (pad->16B-aligned rows), staged by per-lane-row
//     mapping (row = t&63, d-quarter = t>>6) so scalar transposing writes are
//     2-way bank (free); B-frags are plain contiguous bf16x8 reads.
// P : per-wave LDS [16 q][72 kv] row-major; scalar writes, bf16x8 A-frag reads.
// All MFMA operands use the contiguous-K slot convention verified end-to-end
// by gemm_mfma (k-slot permutation cancels between A and B).
// ---------------------------------------------------------------------------
__global__ __launch_bounds__(256) void attn_mfma_kernel(const float* __restrict__ qkv,
                                                        float* __restrict__ o)
{
    const int qt = blockIdx.x, h = blockIdx.y, b = blockIdx.z;
    const int q0 = qt * 64;
    const int t = threadIdx.x;
    const int w = t >> 6, l = t & 63;
    const int r = l & 15, g = l >> 4;
    const size_t rowbase = (size_t)b * T_;
    const int hoff = h * D_;

    __shared__ ushort_t Khi[64*64], Klo[64*64];      // 16 KiB
    __shared__ ushort_t VThi[64*72], VTlo[64*72];    // 18 KiB
    __shared__ ushort_t Ph[4*16*72], Pl[4*16*72];    // 18 KiB

    // ---- Q fragments from global, hi/lo split (A-frag: row=l&15, k=32ks+8g+j) ----
    bf16x8 qh[2], ql[2];
    {
        const float* qrow = qkv + (rowbase + q0 + 16*w + r) * (size_t)(3*M_) + hoff;
        #pragma unroll
        for (int ks = 0; ks < 2; ++ks) {
            const float4 f0 = *reinterpret_cast<const float4*>(qrow + 32*ks + 8*g);
            const float4 f1 = *reinterpret_cast<const float4*>(qrow + 32*ks + 8*g + 4);
            split8(f0, f1, &qh[ks], &ql[ks]);
        }
    }

    // K staging geometry: thread t covers kv-row sr = t>>2, d in [sd, sd+16)
    const int sr = t >> 2, sd = (t & 3) * 16;
    const unsigned ksw = (unsigned)((sr & 7) << 4);
    const unsigned kw0 = (unsigned)(sr * 128) + ((unsigned)(2*sd) ^ ksw);
    const unsigned kw1 = (unsigned)(sr * 128) + ((unsigned)(2*sd + 16) ^ ksw);
    // V staging geometry: thread t covers kv-row vr = t&63, d in [vd, vd+16)
    const int vr = t & 63, vd = (t >> 6) * 16;

    f32x4 oa[4] = {};                       // O acc: df block = d-cols 16df..16df+15
    float mrow[4] = {-__builtin_inff(), -__builtin_inff(), -__builtin_inff(), -__builtin_inff()};
    float lrow[4] = {};

    for (int kt = 0; kt <= qt; ++kt) {
        __syncthreads();                    // prior tile's K/V/P reads done
        // ---- stage K (swizzled row-major) and V (transposed) ----
        {
            const float* kp = qkv + (rowbase + kt*64 + sr) * (size_t)(3*M_) + hoff + M_ + sd;
            const float4 k0 = *reinterpret_cast<const float4*>(kp);
            const float4 k1 = *reinterpret_cast<const float4*>(kp + 4);
            const float4 k2 = *reinterpret_cast<const float4*>(kp + 8);
            const float4 k3 = *reinterpret_cast<const float4*>(kp + 12);
            bf16x8 h0, l0, h1, l1;
            split8(k0, k1, &h0, &l0);
            split8(k2, k3, &h1, &l1);
            *reinterpret_cast<bf16x8*>((char*)Khi + kw0) = h0;
            *reinterpret_cast<bf16x8*>((char*)Khi + kw1) = h1;
            *reinterpret_cast<bf16x8*>((char*)Klo + kw0) = l0;
            *reinterpret_cast<bf16x8*>((char*)Klo + kw1) = l1;

            const float* vp = qkv + (rowbase + kt*64 + vr) * (size_t)(3*M_) + hoff + 2*M_ + vd;
            const float4 v0 = *reinterpret_cast<const float4*>(vp);
            const float4 v1 = *reinterpret_cast<const float4*>(vp + 4);
            const float4 v2 = *reinterpret_cast<const float4*>(vp + 8);
            const float4 v3 = *reinterpret_cast<const float4*>(vp + 12);
            bf16x8 vh0, vl0, vh1, vl1;
            split8(v0, v1, &vh0, &vl0);
            split8(v2, v3, &vh1, &vl1);
            #pragma unroll
            for (int dd = 0; dd < 8; ++dd) {
                VThi[(vd + dd) * 72 + vr]     = (ushort_t)vh0[dd];
                VThi[(vd + 8 + dd) * 72 + vr] = (ushort_t)vh1[dd];
                VTlo[(vd + dd) * 72 + vr]     = (ushort_t)vl0[dd];
                VTlo[(vd + 8 + dd) * 72 + vr] = (ushort_t)vl1[dd];
            }
        }
        __syncthreads();

        // ---- QK^T: S[16 q][64 kv], bf16x3 ----
        f32x4 sa[4] = {};
        #pragma unroll
        for (int ks = 0; ks < 2; ++ks) {
            bf16x8 kh[4], kl[4];
            #pragma unroll
            for (int nf = 0; nf < 4; ++nf) {
                const int row = 16*nf + r;
                const unsigned boff = (unsigned)(row * 128)
                    + (((unsigned)(ks*64 + g*16)) ^ ((unsigned)((row & 7) << 4)));
                kh[nf] = *reinterpret_cast<const bf16x8*>((const char*)Khi + boff);
                kl[nf] = *reinterpret_cast<const bf16x8*>((const char*)Klo + boff);
            }
            #pragma unroll
            for (int nf = 0; nf < 4; ++nf) {
                sa[nf] = __builtin_amdgcn_mfma_f32_16x16x32_bf16(qh[ks], kh[nf], sa[nf], 0, 0, 0);
                sa[nf] = __builtin_amdgcn_mfma_f32_16x16x32_bf16(ql[ks], kh[nf], sa[nf], 0, 0, 0);
                sa[nf] = __builtin_amdgcn_mfma_f32_16x16x32_bf16(qh[ks], kl[nf], sa[nf], 0, 0, 0);
            }
        }

        // ---- scale + causal mask (D layout: col=l&15=kv, row=4g+i=q) ----
        float sv[4][4];
        #pragma unroll
        for (int nf = 0; nf < 4; ++nf)
            #pragma unroll
            for (int i = 0; i < 4; ++i)
                sv[nf][i] = sa[nf][i] * 0.125f;
        if (kt == qt) {
            #pragma unroll
            for (int nf = 0; nf < 4; ++nf) {
                const int kvg = kt*64 + 16*nf + r;
                #pragma unroll
                for (int i = 0; i < 4; ++i) {
                    const int qg = q0 + 16*w + 4*g + i;
                    if (kvg > qg) sv[nf][i] = -3.0e38f;
                }
            }
        }

        // ---- online softmax (reduce over kv: serial nf + shfl over l&15) ----
        float tmax[4];
        #pragma unroll
        for (int i = 0; i < 4; ++i)
            tmax[i] = fmaxf(fmaxf(sv[0][i], sv[1][i]), fmaxf(sv[2][i], sv[3][i]));
        #pragma unroll
        for (int off = 1; off < 16; off <<= 1)
            #pragma unroll
            for (int i = 0; i < 4; ++i)
                tmax[i] = fmaxf(tmax[i], __shfl_xor(tmax[i], off));
        float mnew[4], corr[4];
        #pragma unroll
        for (int i = 0; i < 4; ++i) {
            mnew[i] = fmaxf(mrow[i], tmax[i]);
            corr[i] = expf(mrow[i] - mnew[i]);
        }
        float p[4][4];
        float rsum[4] = {};
        #pragma unroll
        for (int nf = 0; nf < 4; ++nf)
            #pragma unroll
            for (int i = 0; i < 4; ++i) {
                p[nf][i] = expf(sv[nf][i] - mnew[i]);
                rsum[i] += p[nf][i];
            }
        #pragma unroll
        for (int off = 1; off < 16; off <<= 1)
            #pragma unroll
            for (int i = 0; i < 4; ++i)
                rsum[i] += __shfl_xor(rsum[i], off);
        #pragma unroll
        for (int i = 0; i < 4; ++i) {
            lrow[i] = lrow[i] * corr[i] + rsum[i];
            mrow[i] = mnew[i];
        }
        #pragma unroll
        for (int df = 0; df < 4; ++df)
            #pragma unroll
            for (int i = 0; i < 4; ++i)
                oa[df][i] *= corr[i];

        // ---- write P (per-wave [16 q][72 kv], hi/lo, scalar b16 writes) ----
        #pragma unroll
        for (int nf = 0; nf < 4; ++nf) {
            const int kv = 16*nf + r;
            #pragma unroll
            for (int i = 0; i < 4; ++i) {
                const ushort_t phb = f2bf(p[nf][i]);
                Ph[(w*16 + 4*g + i) * 72 + kv] = phb;
                Pl[(w*16 + 4*g + i) * 72 + kv] = f2bf(p[nf][i] - bf2f(phb));
            }
        }
        lgkm0();   // drain P writes; asm memory clobber orders the C++ reads below

        // ---- PV: O += P·V, bf16x3, plain contiguous LDS frag reads ----
        #pragma unroll
        for (int ks = 0; ks < 2; ++ks) {
            const bf16x8 ph = *reinterpret_cast<const bf16x8*>(&Ph[(w*16 + r) * 72 + 32*ks + 8*g]);
            const bf16x8 pl = *reinterpret_cast<const bf16x8*>(&Pl[(w*16 + r) * 72 + 32*ks + 8*g]);
            #pragma unroll
            for (int df = 0; df < 4; ++df) {
                const bf16x8 vhf = *reinterpret_cast<const bf16x8*>(&VThi[(16*df + r) * 72 + 32*ks + 8*g]);
                const bf16x8 vlf = *reinterpret_cast<const bf16x8*>(&VTlo[(16*df + r) * 72 + 32*ks + 8*g]);
                oa[df] = __builtin_amdgcn_mfma_f32_16x16x32_bf16(ph, vhf, oa[df], 0, 0, 0);
                oa[df] = __builtin_amdgcn_mfma_f32_16x16x32_bf16(pl, vhf, oa[df], 0, 0, 0);
                oa[df] = __builtin_amdgcn_mfma_f32_16x16x32_bf16(ph, vlf, oa[df], 0, 0, 0);
            }
        }
    }

    // ---- epilogue: o[q][hoff + d] = O / l  (D: col=l&15=d, row=4g+i=q) ----
    #pragma unroll
    for (int i = 0; i < 4; ++i) {
        const float inv = 1.0f / lrow[i];
        const size_t row = (rowbase + q0 + 16*w + 4*g + i) * (size_t)M_ + hoff;
        #pragma unroll
        for (int df = 0; df < 4; ++df)
            o[row + 16*df + r] = oa[df][i] * inv;
    }
}

// ---------------------------------------------------------------------------
// Router + deepspeed dispatch bookkeeping (exact, f32).
// ---------------------------------------------------------------------------
__global__ __launch_bounds__(256) void gate_kernel(const float* __restrict__ h2,
                                                   const float* __restrict__ wg,
                                                   int* __restrict__ gidx,
                                                   float* __restrict__ gtop)
{
    const int s = blockIdx.x;
    const int e = threadIdx.x >> 5;
    const int l = threadIdx.x & 31;
    const float* row = h2 + (size_t)s * M_;
    float acc = 0.0f;
    for (int m = l; m < M_; m += 32) acc = fmaf(row[m], wg[m * E_ + e], acc);
    #pragma unroll
    for (int off = 16; off > 0; off >>= 1) acc += __shfl_down(acc, off, 32);
    __shared__ float lg[E_];
    if (l == 0) lg[e] = acc;
    __syncthreads();
    if (threadIdx.x == 0) {
        float mx = lg[0]; int bi = 0;
        #pragma unroll
        for (int i = 1; i < E_; ++i) { if (lg[i] > mx) { mx = lg[i]; bi = i; } }
        float den = 0.0f;
        #pragma unroll
        for (int i = 0; i < E_; ++i) den += expf(lg[i] - mx);
        gidx[s] = bi;
        gtop[s] = 1.0f / den;
    }
}

__global__ __launch_bounds__(1024) void scan_kernel(const int* __restrict__ gidx,
                                                    const float* __restrict__ gtop,
                                                    float* __restrict__ gate_val,
                                                    int* __restrict__ token_at)
{
    __shared__ int hist[1024][E_];
    const int tid = threadIdx.x;
    for (int i = tid; i < E_ * C_; i += 1024) token_at[i] = -1;
    int my[8];
    #pragma unroll
    for (int t = 0; t < 8; ++t) my[t] = gidx[tid * 8 + t];
    #pragma unroll
    for (int e = 0; e < E_; ++e) {
        int c = 0;
        #pragma unroll
        for (int t = 0; t < 8; ++t) c += (my[t] == e) ? 1 : 0;
        hist[tid][e] = c;
    }
    __syncthreads();
    if (tid < E_) {
        int run = 0;
        for (int t = 0; t < 1024; ++t) {
            const int v = hist[t][tid];
            hist[t][tid] = run;
            run += v;
        }
    }
    __syncthreads();
    #pragma unroll
    for (int t = 0; t < 8; ++t) {
        const int s = tid * 8 + t;
        const int e = my[t];
        const int p = hist[tid][e];
        hist[tid][e] = p + 1;
        const bool keep = (p < C_);
        gate_val[s] = keep ? gtop[s] : 0.0f;
        if (keep) token_at[e * C_ + p] = s;
    }
}

// Gather-dispatch straight to bf16 [E][C][M].
__global__ __launch_bounds__(256) void dispatch_bf16_kernel(const float* __restrict__ h2,
                                                            const int* __restrict__ token_at,
                                                            ushort_t* __restrict__ disp)
{
    const int ec = blockIdx.x;
    const int s = token_at[ec];
    ushort4* dst = reinterpret_cast<ushort4*>(disp + (size_t)ec * M_);
    if (s >= 0) {
        const float4 v = reinterpret_cast<const float4*>(h2 + (size_t)s * M_)[threadIdx.x];
        dst[threadIdx.x] = make_ushort4(f2bf(v.x), f2bf(v.y), f2bf(v.z), f2bf(v.w));
    } else {
        dst[threadIdx.x] = make_ushort4(0, 0, 0, 0);
    }
}

// Transpose+convert: in[e][R][Cc] f32 -> out[e][Cc][R] bf16.
__global__ __launch_bounds__(256) void transpose_bf16_kernel(const float* __restrict__ in,
                                                             ushort_t* __restrict__ outp,
                                                             int R, int Cc)
{
    __shared__ float tile[32][33];
    const int e = blockIdx.z;
    in   += (size_t)e * R * Cc;
    outp += (size_t)e * R * Cc;
    const int tx = threadIdx.x & 31, ty0 = threadIdx.x >> 5;
    const int c0 = blockIdx.x * 32, r0 = blockIdx.y * 32;
    #pragma unroll
    for (int i = 0; i < 4; ++i)
        tile[ty0 + 8*i][tx] = in[(size_t)(r0 + ty0 + 8*i) * Cc + c0 + tx];
    __syncthreads();
    #pragma unroll
    for (int i = 0; i < 4; ++i)
        outp[(size_t)(c0 + ty0 + 8*i) * R + r0 + tx] = f2bf(tile[tx][ty0 + 8*i]);
}

// ---------------------------------------------------------------------------
// bf16 MFMA GEMM, m97 structure (MoE FFN, post-router).
// EPI 0: h1 = bf16(gelu(acc + bias)); EPI 1: scatter-combine into out.
// ---------------------------------------------------------------------------
template<int EPI>
__global__ __launch_bounds__(256) void gemm_mfma(
    const ushort_t* __restrict__ A, const ushort_t* __restrict__ Bt,
    const float* __restrict__ bias,
    const int* __restrict__ token_at, const float* __restrict__ gate_val,
    void* __restrict__ Cout, int N, int K,
    long strA, long strB, long strBias, long strC)
{
    const int e = blockIdx.z;
    A    += (size_t)e * (size_t)strA;
    Bt   += (size_t)e * (size_t)strB;
    bias += (size_t)e * (size_t)strBias;

    __shared__ ushort_t As[128 * 32];
    __shared__ ushort_t Bs[128 * 32];

    const int t  = threadIdx.x;
    const int l  = t & 63;
    const int wv = t >> 6;
    const int wm = (wv & 1) * 64, wn = (wv >> 1) * 64;
    const int fr = l & 15, fk = (l >> 4) * 8;
    const int m0 = blockIdx.y * 128, n0 = blockIdx.x * 128;

    const ushort_t* gA = A + (size_t)(m0 + (t >> 2)) * K + (t & 3) * 8;
    const ushort_t* gB = Bt + (size_t)(n0 + (t >> 2)) * K + (t & 3) * 8;
    ushort_t* lA = As + wv * 512;
    ushort_t* lB = Bs + wv * 512;

    f32x4 acc[4][4] = {};

    for (int k0 = 0; k0 < K; k0 += 32) {
        __syncthreads();
        gload_lds16(gA + k0, lA);
        gload_lds16(gA + k0 + (size_t)64 * K, lA + 2048);
        gload_lds16(gB + k0, lB);
        gload_lds16(gB + k0 + (size_t)64 * K, lB + 2048);
        __syncthreads();
        bf16x8 af[4], bfr[4];
        #pragma unroll
        for (int i = 0; i < 4; ++i)
            af[i] = *reinterpret_cast<const bf16x8*>(&As[(wm + i*16 + fr) * 32 + fk]);
        #pragma unroll
        for (int i = 0; i < 4; ++i)
            bfr[i] = *reinterpret_cast<const bf16x8*>(&Bs[(wn + i*16 + fr) * 32 + fk]);
        #pragma unroll
        for (int mi = 0; mi < 4; ++mi) {
            #pragma unroll
            for (int ni = 0; ni < 4; ++ni)
                acc[mi][ni] = __builtin_amdgcn_mfma_f32_16x16x32_bf16(
                    af[mi], bfr[ni], acc[mi][ni], 0, 0, 0);
        }
    }

    const int l4 = (l >> 4) * 4;
    if (EPI == 0) {
        ushort_t* Cc = (ushort_t*)Cout + (size_t)e * (size_t)strC;
        #pragma unroll
        for (int ni = 0; ni < 4; ++ni) {
            const int cl = n0 + wn + ni*16 + fr;
            const float bb = bias[cl];
            #pragma unroll
            for (int mi = 0; mi < 4; ++mi) {
                #pragma unroll
                for (int i = 0; i < 4; ++i) {
                    const int rr = m0 + wm + mi*16 + l4 + i;
                    Cc[(size_t)rr * N + cl] = f2bf(gelu_exact(acc[mi][ni][i] + bb));
                }
            }
        }
    } else {
        float* Co = (float*)Cout;
        const int* ta = token_at + e * C_;
        #pragma unroll
        for (int mi = 0; mi < 4; ++mi) {
            #pragma unroll
            for (int i = 0; i < 4; ++i) {
                const int rr = m0 + wm + mi*16 + l4 + i;
                const int s = ta[rr];
                if (s >= 0) {
                    const float gvl = gate_val[s];
                    #pragma unroll
                    for (int ni = 0; ni < 4; ++ni) {
                        const int cl = n0 + wn + ni*16 + fr;
                        Co[(size_t)s * N + cl] += gvl * (acc[mi][ni][i] + bias[cl]);
                    }
                }
            }
        }
    }
}

// ---------------------------------------------------------------------------
extern "C" void kernel_launch(void* const* d_in, const int* in_sizes, int n_in,
                              void* d_out, int out_size, void* d_ws, size_t ws_size,
                              hipStream_t stream)
{
    const float* x    = (const float*)d_in[0];
    const float* ln1g = (const float*)d_in[1];
    const float* ln1b = (const float*)d_in[2];
    const float* Wqkv = (const float*)d_in[3];
    const float* bqkv = (const float*)d_in[4];
    const float* Wout = (const float*)d_in[5];
    const float* bout = (const float*)d_in[6];
    const float* ln2g = (const float*)d_in[7];
    const float* ln2b = (const float*)d_in[8];
    const float* wg   = (const float*)d_in[9];
    const float* w1   = (const float*)d_in[10];
    const float* b1   = (const float*)d_in[11];
    const float* w2   = (const float*)d_in[12];
    const float* b2   = (const float*)d_in[13];
    float* out = (float*)d_out;

    // Workspace layout (MiB offsets), lifetime-scheduled. Peak ~177 MiB.
    char* ws = (char*)d_ws;
    float*    buf_h   = (float*)ws;                         // [0,32)
    float*    buf_qkv = (float*)(ws + ((size_t)32  << 20)); // [32,128)
    float*    buf_o   = (float*)(ws + ((size_t)128 << 20)); // [128,160)
    ushort_t* w1t     = (ushort_t*)(ws + ((size_t)32  << 20));
    ushort_t* w2t     = (ushort_t*)(ws + ((size_t)32  << 20));
    ushort_t* dispb   = (ushort_t*)(ws + ((size_t)96  << 20));
    ushort_t* h1b     = (ushort_t*)(ws + ((size_t)112 << 20));
    float*    buf_gtop= (float*)(ws + ((size_t)176 << 20));
    float*    buf_gv  = buf_gtop + S_;
    int*      buf_idx = (int*)(buf_gv + S_);
    int*      buf_ta  = buf_idx + S_;

    // --- pre-router path (f32-grade) ---
    ln_kernel<<<S_, 256, 0, stream>>>(x, ln1g, ln1b, buf_h);
    gemm_f32<true, 0><<<dim3(3*M_/128, S_/128, 1), 256, 0, stream>>>(
        buf_h, Wqkv, bqkv, nullptr, buf_qkv, 3*M_, M_);
    attn_mfma_kernel<<<dim3(T_/64, H_, B_), 256, 0, stream>>>(buf_qkv, buf_o);
    gemm_f32<true, 1><<<dim3(M_/128, S_/128, 1), 256, 0, stream>>>(
        buf_o, Wout, bout, x, out, M_, M_);
    ln_kernel<<<S_, 256, 0, stream>>>(out, ln2g, ln2b, buf_h);
    gate_kernel<<<S_, 256, 0, stream>>>(buf_h, wg, buf_idx, buf_gtop);
    scan_kernel<<<1, 1024, 0, stream>>>(buf_idx, buf_gtop, buf_gv, buf_ta);
    dispatch_bf16_kernel<<<E_*C_, 256, 0, stream>>>(buf_h, buf_ta, dispb);

    // --- MoE FFN (bf16 MFMA, post-router) ---
    transpose_bf16_kernel<<<dim3(F_/32, M_/32, E_), 256, 0, stream>>>(w1, w1t, M_, F_);
    gemm_mfma<0><<<dim3(F_/128, C_/128, E_), 256, 0, stream>>>(
        dispb, w1t, b1, nullptr, nullptr, h1b, F_, M_,
        (long)C_*M_, (long)F_*M_, (long)F_, (long)C_*F_);
    transpose_bf16_kernel<<<dim3(M_/32, F_/32, E_), 256, 0, stream>>>(w2, w2t, F_, M_);
    gemm_mfma<1><<<dim3(M_/128, C_/128, E_), 256, 0, stream>>>(
        h1b, w2t, b2, buf_ta, buf_gv, out, M_, F_,
        (long)C_*F_, (long)M_*F_, (long)M_, 0);
}

// Round 5
// 1250.532 us; speedup vs baseline: 3.0132x; 1.4770x over previous
//
#include <hip/hip_runtime.h>
#include <hip/hip_bf16.h>
#include <math.h>

#define B_ 4
#define T_ 2048
#define M_ 1024
#define H_ 16
#define E_ 8
#define S_ (B_*T_)      // 8192
#define C_ (S_/E_)      // 1024
#define D_ (M_/H_)      // 64
#define F_ (4*M_)       // 4096

typedef unsigned short ushort_t;
typedef __attribute__((ext_vector_type(8))) short bf16x8;
typedef __attribute__((ext_vector_type(4))) float f32x4;

__device__ __forceinline__ float gelu_exact(float x) {
    return 0.5f * x * (1.0f + erff(x * 0.70710678118654752440f));
}

__device__ __forceinline__ unsigned short f2bf(float f) {
    unsigned int u = __float_as_uint(f);
    u = (u + 0x7FFFu + ((u >> 16) & 1u)) >> 16;   // RNE
    return (unsigned short)u;
}

__device__ __forceinline__ float bf2f(unsigned short h) {
    return __uint_as_float(((unsigned)h) << 16);
}

__device__ __forceinline__ void gload_lds16(const void* g, void* l) {
    __builtin_amdgcn_global_load_lds(
        (const __attribute__((address_space(1))) unsigned int*)g,
        (__attribute__((address_space(3))) unsigned int*)l,
        16, 0, 0);
}

// RNE split: hi = RNE_bf16(f); lo = RNE_bf16(f - hi). hi+lo = f to ~2^-18 rel.
__device__ __forceinline__ void split8(const float4 a, const float4 b,
                                       bf16x8* hi, bf16x8* lo) {
    const float f[8] = {a.x, a.y, a.z, a.w, b.x, b.y, b.z, b.w};
    bf16x8 h, lw;
    #pragma unroll
    for (int j = 0; j < 8; ++j) {
        const unsigned short hb = f2bf(f[j]);
        h[j] = (short)hb;
        lw[j] = (short)f2bf(f[j] - bf2f(hb));
    }
    *hi = h; *lo = lw;
}

__device__ __forceinline__ void lgkm0() {
    asm volatile("s_waitcnt lgkmcnt(0)" ::: "memory");
}

// ---------------------------------------------------------------------------
// LayerNorm (f32 out): one block per row.
// ---------------------------------------------------------------------------
__global__ __launch_bounds__(256) void ln_kernel(const float* __restrict__ x,
                                                 const float* __restrict__ g,
                                                 const float* __restrict__ bta,
                                                 float* __restrict__ out)
{
    const int row = blockIdx.x;
    const int tid = threadIdx.x;
    const float4 v = reinterpret_cast<const float4*>(x + (size_t)row * M_)[tid];
    float s = v.x + v.y + v.z + v.w;
    __shared__ float red[4];
    #pragma unroll
    for (int off = 32; off > 0; off >>= 1) s += __shfl_down(s, off);
    if ((tid & 63) == 0) red[tid >> 6] = s;
    __syncthreads();
    const float mu = (red[0] + red[1] + red[2] + red[3]) * (1.0f / (float)M_);
    __syncthreads();
    float4 d;
    d.x = v.x - mu; d.y = v.y - mu; d.z = v.z - mu; d.w = v.w - mu;
    float q = d.x*d.x + d.y*d.y + d.z*d.z + d.w*d.w;
    #pragma unroll
    for (int off = 32; off > 0; off >>= 1) q += __shfl_down(q, off);
    if ((tid & 63) == 0) red[tid >> 6] = q;
    __syncthreads();
    const float var  = (red[0] + red[1] + red[2] + red[3]) * (1.0f / (float)M_);
    const float rstd = 1.0f / sqrtf(var + 1e-5f);
    const float4 gv = reinterpret_cast<const float4*>(g)[tid];
    const float4 bv = reinterpret_cast<const float4*>(bta)[tid];
    float4 o;
    o.x = d.x * rstd * gv.x + bv.x;
    o.y = d.y * rstd * gv.y + bv.y;
    o.z = d.z * rstd * gv.z + bv.z;
    o.w = d.w * rstd * gv.w + bv.w;
    reinterpret_cast<float4*>(out + (size_t)row * M_)[tid] = o;
}

// LayerNorm fused with hi/lo bf16 split output (A-operand producer).
__global__ __launch_bounds__(256) void ln_split_kernel(const float* __restrict__ x,
                                                       const float* __restrict__ g,
                                                       const float* __restrict__ bta,
                                                       ushort_t* __restrict__ hi,
                                                       ushort_t* __restrict__ lo)
{
    const int row = blockIdx.x;
    const int tid = threadIdx.x;
    const float4 v = reinterpret_cast<const float4*>(x + (size_t)row * M_)[tid];
    float s = v.x + v.y + v.z + v.w;
    __shared__ float red[4];
    #pragma unroll
    for (int off = 32; off > 0; off >>= 1) s += __shfl_down(s, off);
    if ((tid & 63) == 0) red[tid >> 6] = s;
    __syncthreads();
    const float mu = (red[0] + red[1] + red[2] + red[3]) * (1.0f / (float)M_);
    __syncthreads();
    float4 d;
    d.x = v.x - mu; d.y = v.y - mu; d.z = v.z - mu; d.w = v.w - mu;
    float q = d.x*d.x + d.y*d.y + d.z*d.z + d.w*d.w;
    #pragma unroll
    for (int off = 32; off > 0; off >>= 1) q += __shfl_down(q, off);
    if ((tid & 63) == 0) red[tid >> 6] = q;
    __syncthreads();
    const float var  = (red[0] + red[1] + red[2] + red[3]) * (1.0f / (float)M_);
    const float rstd = 1.0f / sqrtf(var + 1e-5f);
    const float4 gv = reinterpret_cast<const float4*>(g)[tid];
    const float4 bv = reinterpret_cast<const float4*>(bta)[tid];
    float o[4];
    o[0] = d.x * rstd * gv.x + bv.x;
    o[1] = d.y * rstd * gv.y + bv.y;
    o[2] = d.z * rstd * gv.z + bv.z;
    o[3] = d.w * rstd * gv.w + bv.w;
    ushort4 hh, ll;
    hh.x = f2bf(o[0]); ll.x = f2bf(o[0] - bf2f(hh.x));
    hh.y = f2bf(o[1]); ll.y = f2bf(o[1] - bf2f(hh.y));
    hh.z = f2bf(o[2]); ll.z = f2bf(o[2] - bf2f(hh.z));
    hh.w = f2bf(o[3]); ll.w = f2bf(o[3] - bf2f(hh.w));
    reinterpret_cast<ushort4*>(hi + (size_t)row * M_)[tid] = hh;
    reinterpret_cast<ushort4*>(lo + (size_t)row * M_)[tid] = ll;
}

// Elementwise f32 -> hi/lo bf16 split (weights, attention output).
__global__ __launch_bounds__(256) void split_kernel(const float* __restrict__ in,
                                                    ushort_t* __restrict__ hi,
                                                    ushort_t* __restrict__ lo,
                                                    int n4)
{
    const int i = blockIdx.x * 256 + threadIdx.x;
    if (i >= n4) return;
    const float4 v = reinterpret_cast<const float4*>(in)[i];
    ushort4 hh, ll;
    hh.x = f2bf(v.x); ll.x = f2bf(v.x - bf2f(hh.x));
    hh.y = f2bf(v.y); ll.y = f2bf(v.y - bf2f(hh.y));
    hh.z = f2bf(v.z); ll.z = f2bf(v.z - bf2f(hh.z));
    hh.w = f2bf(v.w); ll.w = f2bf(v.w - bf2f(hh.w));
    reinterpret_cast<ushort4*>(hi)[i] = hh;
    reinterpret_cast<ushort4*>(lo)[i] = ll;
}

// ---------------------------------------------------------------------------
// bf16x3 MFMA GEMM (f32-grade, pre-router path). m97 structure, 4 LDS bufs.
// A hi/lo [rows][K]; B hi/lo [N][K] (weight row-major = [N][K] K-contiguous).
// EPI 0: Cc = acc + bias; EPI 1: Cc = acc + bias + res.
// ---------------------------------------------------------------------------
template<int EPI>
__global__ __launch_bounds__(256) void gemm_bf16x3(
    const ushort_t* __restrict__ Ahi, const ushort_t* __restrict__ Alo,
    const ushort_t* __restrict__ Bhi, const ushort_t* __restrict__ Blo,
    const float* __restrict__ bias, const float* __restrict__ res,
    float* __restrict__ Cc, int N, int K)
{
    __shared__ ushort_t AsH[128*32], AsL[128*32];
    __shared__ ushort_t BsH[128*32], BsL[128*32];

    const int t  = threadIdx.x;
    const int l  = t & 63;
    const int wv = t >> 6;
    const int wm = (wv & 1) * 64, wn = (wv >> 1) * 64;
    const int fr = l & 15, fk = (l >> 4) * 8;
    const int m0 = blockIdx.y * 128, n0 = blockIdx.x * 128;

    const size_t arow = (size_t)(m0 + (t >> 2)) * K + (t & 3) * 8;
    const size_t brow = (size_t)(n0 + (t >> 2)) * K + (t & 3) * 8;
    ushort_t* lAH = AsH + wv * 512;
    ushort_t* lAL = AsL + wv * 512;
    ushort_t* lBH = BsH + wv * 512;
    ushort_t* lBL = BsL + wv * 512;

    f32x4 acc[4][4] = {};

    for (int k0 = 0; k0 < K; k0 += 32) {
        __syncthreads();
        gload_lds16(Ahi + arow + k0, lAH);
        gload_lds16(Ahi + arow + k0 + (size_t)64 * K, lAH + 2048);
        gload_lds16(Alo + arow + k0, lAL);
        gload_lds16(Alo + arow + k0 + (size_t)64 * K, lAL + 2048);
        gload_lds16(Bhi + brow + k0, lBH);
        gload_lds16(Bhi + brow + k0 + (size_t)64 * K, lBH + 2048);
        gload_lds16(Blo + brow + k0, lBL);
        gload_lds16(Blo + brow + k0 + (size_t)64 * K, lBL + 2048);
        __syncthreads();
        bf16x8 ah[4], al[4], bh[4], bl[4];
        #pragma unroll
        for (int i = 0; i < 4; ++i) {
            ah[i] = *reinterpret_cast<const bf16x8*>(&AsH[(wm + i*16 + fr) * 32 + fk]);
            al[i] = *reinterpret_cast<const bf16x8*>(&AsL[(wm + i*16 + fr) * 32 + fk]);
            bh[i] = *reinterpret_cast<const bf16x8*>(&BsH[(wn + i*16 + fr) * 32 + fk]);
            bl[i] = *reinterpret_cast<const bf16x8*>(&BsL[(wn + i*16 + fr) * 32 + fk]);
        }
        #pragma unroll
        for (int mi = 0; mi < 4; ++mi) {
            #pragma unroll
            for (int ni = 0; ni < 4; ++ni) {
                acc[mi][ni] = __builtin_amdgcn_mfma_f32_16x16x32_bf16(ah[mi], bh[ni], acc[mi][ni], 0, 0, 0);
                acc[mi][ni] = __builtin_amdgcn_mfma_f32_16x16x32_bf16(al[mi], bh[ni], acc[mi][ni], 0, 0, 0);
                acc[mi][ni] = __builtin_amdgcn_mfma_f32_16x16x32_bf16(ah[mi], bl[ni], acc[mi][ni], 0, 0, 0);
            }
        }
    }

    // C/D: col = lane&15, row = (lane>>4)*4 + reg
    const int l4 = (l >> 4) * 4;
    #pragma unroll
    for (int mi = 0; mi < 4; ++mi) {
        #pragma unroll
        for (int i = 0; i < 4; ++i) {
            const int row = m0 + wm + mi*16 + l4 + i;
            #pragma unroll
            for (int ni = 0; ni < 4; ++ni) {
                const int col = n0 + wn + ni*16 + fr;
                float v = acc[mi][ni][i] + bias[col];
                if (EPI == 1) v += res[(size_t)row * N + col];
                Cc[(size_t)row * N + col] = v;
            }
        }
    }
}

// ---------------------------------------------------------------------------
// bf16x3 MFMA flash attention (unchanged from round 4 — verified).
// ---------------------------------------------------------------------------
__global__ __launch_bounds__(256) void attn_mfma_kernel(const float* __restrict__ qkv,
                                                        float* __restrict__ o)
{
    const int qt = blockIdx.x, h = blockIdx.y, b = blockIdx.z;
    const int q0 = qt * 64;
    const int t = threadIdx.x;
    const int w = t >> 6, l = t & 63;
    const int r = l & 15, g = l >> 4;
    const size_t rowbase = (size_t)b * T_;
    const int hoff = h * D_;

    __shared__ ushort_t Khi[64*64], Klo[64*64];
    __shared__ ushort_t VThi[64*72], VTlo[64*72];
    __shared__ ushort_t Ph[4*16*72], Pl[4*16*72];

    bf16x8 qh[2], ql[2];
    {
        const float* qrow = qkv + (rowbase + q0 + 16*w + r) * (size_t)(3*M_) + hoff;
        #pragma unroll
        for (int ks = 0; ks < 2; ++ks) {
            const float4 f0 = *reinterpret_cast<const float4*>(qrow + 32*ks + 8*g);
            const float4 f1 = *reinterpret_cast<const float4*>(qrow + 32*ks + 8*g + 4);
            split8(f0, f1, &qh[ks], &ql[ks]);
        }
    }

    const int sr = t >> 2, sd = (t & 3) * 16;
    const unsigned ksw = (unsigned)((sr & 7) << 4);
    const unsigned kw0 = (unsigned)(sr * 128) + ((unsigned)(2*sd) ^ ksw);
    const unsigned kw1 = (unsigned)(sr * 128) + ((unsigned)(2*sd + 16) ^ ksw);
    const int vr = t & 63, vd = (t >> 6) * 16;

    f32x4 oa[4] = {};
    float mrow[4] = {-__builtin_inff(), -__builtin_inff(), -__builtin_inff(), -__builtin_inff()};
    float lrow[4] = {};

    for (int kt = 0; kt <= qt; ++kt) {
        __syncthreads();
        {
            const float* kp = qkv + (rowbase + kt*64 + sr) * (size_t)(3*M_) + hoff + M_ + sd;
            const float4 k0 = *reinterpret_cast<const float4*>(kp);
            const float4 k1 = *reinterpret_cast<const float4*>(kp + 4);
            const float4 k2 = *reinterpret_cast<const float4*>(kp + 8);
            const float4 k3 = *reinterpret_cast<const float4*>(kp + 12);
            bf16x8 h0, l0, h1, l1;
            split8(k0, k1, &h0, &l0);
            split8(k2, k3, &h1, &l1);
            *reinterpret_cast<bf16x8*>((char*)Khi + kw0) = h0;
            *reinterpret_cast<bf16x8*>((char*)Khi + kw1) = h1;
            *reinterpret_cast<bf16x8*>((char*)Klo + kw0) = l0;
            *reinterpret_cast<bf16x8*>((char*)Klo + kw1) = l1;

            const float* vp = qkv + (rowbase + kt*64 + vr) * (size_t)(3*M_) + hoff + 2*M_ + vd;
            const float4 v0 = *reinterpret_cast<const float4*>(vp);
            const float4 v1 = *reinterpret_cast<const float4*>(vp + 4);
            const float4 v2 = *reinterpret_cast<const float4*>(vp + 8);
            const float4 v3 = *reinterpret_cast<const float4*>(vp + 12);
            bf16x8 vh0, vl0, vh1, vl1;
            split8(v0, v1, &vh0, &vl0);
            split8(v2, v3, &vh1, &vl1);
            #pragma unroll
            for (int dd = 0; dd < 8; ++dd) {
                VThi[(vd + dd) * 72 + vr]     = (ushort_t)vh0[dd];
                VThi[(vd + 8 + dd) * 72 + vr] = (ushort_t)vh1[dd];
                VTlo[(vd + dd) * 72 + vr]     = (ushort_t)vl0[dd];
                VTlo[(vd + 8 + dd) * 72 + vr] = (ushort_t)vl1[dd];
            }
        }
        __syncthreads();

        f32x4 sa[4] = {};
        #pragma unroll
        for (int ks = 0; ks < 2; ++ks) {
            bf16x8 kh[4], kl[4];
            #pragma unroll
            for (int nf = 0; nf < 4; ++nf) {
                const int row = 16*nf + r;
                const unsigned boff = (unsigned)(row * 128)
                    + (((unsigned)(ks*64 + g*16)) ^ ((unsigned)((row & 7) << 4)));
                kh[nf] = *reinterpret_cast<const bf16x8*>((const char*)Khi + boff);
                kl[nf] = *reinterpret_cast<const bf16x8*>((const char*)Klo + boff);
            }
            #pragma unroll
            for (int nf = 0; nf < 4; ++nf) {
                sa[nf] = __builtin_amdgcn_mfma_f32_16x16x32_bf16(qh[ks], kh[nf], sa[nf], 0, 0, 0);
                sa[nf] = __builtin_amdgcn_mfma_f32_16x16x32_bf16(ql[ks], kh[nf], sa[nf], 0, 0, 0);
                sa[nf] = __builtin_amdgcn_mfma_f32_16x16x32_bf16(qh[ks], kl[nf], sa[nf], 0, 0, 0);
            }
        }

        float sv[4][4];
        #pragma unroll
        for (int nf = 0; nf < 4; ++nf)
            #pragma unroll
            for (int i = 0; i < 4; ++i)
                sv[nf][i] = sa[nf][i] * 0.125f;
        if (kt == qt) {
            #pragma unroll
            for (int nf = 0; nf < 4; ++nf) {
                const int kvg = kt*64 + 16*nf + r;
                #pragma unroll
                for (int i = 0; i < 4; ++i) {
                    const int qg = q0 + 16*w + 4*g + i;
                    if (kvg > qg) sv[nf][i] = -3.0e38f;
                }
            }
        }

        float tmax[4];
        #pragma unroll
        for (int i = 0; i < 4; ++i)
            tmax[i] = fmaxf(fmaxf(sv[0][i], sv[1][i]), fmaxf(sv[2][i], sv[3][i]));
        #pragma unroll
        for (int off = 1; off < 16; off <<= 1)
            #pragma unroll
            for (int i = 0; i < 4; ++i)
                tmax[i] = fmaxf(tmax[i], __shfl_xor(tmax[i], off));
        float mnew[4], corr[4];
        #pragma unroll
        for (int i = 0; i < 4; ++i) {
            mnew[i] = fmaxf(mrow[i], tmax[i]);
            corr[i] = expf(mrow[i] - mnew[i]);
        }
        float p[4][4];
        float rsum[4] = {};
        #pragma unroll
        for (int nf = 0; nf < 4; ++nf)
            #pragma unroll
            for (int i = 0; i < 4; ++i) {
                p[nf][i] = expf(sv[nf][i] - mnew[i]);
                rsum[i] += p[nf][i];
            }
        #pragma unroll
        for (int off = 1; off < 16; off <<= 1)
            #pragma unroll
            for (int i = 0; i < 4; ++i)
                rsum[i] += __shfl_xor(rsum[i], off);
        #pragma unroll
        for (int i = 0; i < 4; ++i) {
            lrow[i] = lrow[i] * corr[i] + rsum[i];
            mrow[i] = mnew[i];
        }
        #pragma unroll
        for (int df = 0; df < 4; ++df)
            #pragma unroll
            for (int i = 0; i < 4; ++i)
                oa[df][i] *= corr[i];

        #pragma unroll
        for (int nf = 0; nf < 4; ++nf) {
            const int kv = 16*nf + r;
            #pragma unroll
            for (int i = 0; i < 4; ++i) {
                const ushort_t phb = f2bf(p[nf][i]);
                Ph[(w*16 + 4*g + i) * 72 + kv] = phb;
                Pl[(w*16 + 4*g + i) * 72 + kv] = f2bf(p[nf][i] - bf2f(phb));
            }
        }
        lgkm0();

        #pragma unroll
        for (int ks = 0; ks < 2; ++ks) {
            const bf16x8 ph = *reinterpret_cast<const bf16x8*>(&Ph[(w*16 + r) * 72 + 32*ks + 8*g]);
            const bf16x8 pl = *reinterpret_cast<const bf16x8*>(&Pl[(w*16 + r) * 72 + 32*ks + 8*g]);
            #pragma unroll
            for (int df = 0; df < 4; ++df) {
                const bf16x8 vhf = *reinterpret_cast<const bf16x8*>(&VThi[(16*df + r) * 72 + 32*ks + 8*g]);
                const bf16x8 vlf = *reinterpret_cast<const bf16x8*>(&VTlo[(16*df + r) * 72 + 32*ks + 8*g]);
                oa[df] = __builtin_amdgcn_mfma_f32_16x16x32_bf16(ph, vhf, oa[df], 0, 0, 0);
                oa[df] = __builtin_amdgcn_mfma_f32_16x16x32_bf16(pl, vhf, oa[df], 0, 0, 0);
                oa[df] = __builtin_amdgcn_mfma_f32_16x16x32_bf16(ph, vlf, oa[df], 0, 0, 0);
            }
        }
    }

    #pragma unroll
    for (int i = 0; i < 4; ++i) {
        const float inv = 1.0f / lrow[i];
        const size_t row = (rowbase + q0 + 16*w + 4*g + i) * (size_t)M_ + hoff;
        #pragma unroll
        for (int df = 0; df < 4; ++df)
            o[row + 16*df + r] = oa[df][i] * inv;
    }
}

// ---------------------------------------------------------------------------
// Router + deepspeed dispatch bookkeeping (exact, f32).
// ---------------------------------------------------------------------------
__global__ __launch_bounds__(256) void gate_kernel(const float* __restrict__ h2,
                                                   const float* __restrict__ wg,
                                                   int* __restrict__ gidx,
                                                   float* __restrict__ gtop)
{
    const int s = blockIdx.x;
    const int e = threadIdx.x >> 5;
    const int l = threadIdx.x & 31;
    const float* row = h2 + (size_t)s * M_;
    float acc = 0.0f;
    for (int m = l; m < M_; m += 32) acc = fmaf(row[m], wg[m * E_ + e], acc);
    #pragma unroll
    for (int off = 16; off > 0; off >>= 1) acc += __shfl_down(acc, off, 32);
    __shared__ float lg[E_];
    if (l == 0) lg[e] = acc;
    __syncthreads();
    if (threadIdx.x == 0) {
        float mx = lg[0]; int bi = 0;
        #pragma unroll
        for (int i = 1; i < E_; ++i) { if (lg[i] > mx) { mx = lg[i]; bi = i; } }
        float den = 0.0f;
        #pragma unroll
        for (int i = 0; i < E_; ++i) den += expf(lg[i] - mx);
        gidx[s] = bi;
        gtop[s] = 1.0f / den;
    }
}

__global__ __launch_bounds__(1024) void scan_kernel(const int* __restrict__ gidx,
                                                    const float* __restrict__ gtop,
                                                    float* __restrict__ gate_val,
                                                    int* __restrict__ token_at)
{
    __shared__ int hist[1024][E_];
    const int tid = threadIdx.x;
    for (int i = tid; i < E_ * C_; i += 1024) token_at[i] = -1;
    int my[8];
    #pragma unroll
    for (int t = 0; t < 8; ++t) my[t] = gidx[tid * 8 + t];
    #pragma unroll
    for (int e = 0; e < E_; ++e) {
        int c = 0;
        #pragma unroll
        for (int t = 0; t < 8; ++t) c += (my[t] == e) ? 1 : 0;
        hist[tid][e] = c;
    }
    __syncthreads();
    if (tid < E_) {
        int run = 0;
        for (int t = 0; t < 1024; ++t) {
            const int v = hist[t][tid];
            hist[t][tid] = run;
            run += v;
        }
    }
    __syncthreads();
    #pragma unroll
    for (int t = 0; t < 8; ++t) {
        const int s = tid * 8 + t;
        const int e = my[t];
        const int p = hist[tid][e];
        hist[tid][e] = p + 1;
        const bool keep = (p < C_);
        gate_val[s] = keep ? gtop[s] : 0.0f;
        if (keep) token_at[e * C_ + p] = s;
    }
}

__global__ __launch_bounds__(256) void dispatch_bf16_kernel(const float* __restrict__ h2,
                                                            const int* __restrict__ token_at,
                                                            ushort_t* __restrict__ disp)
{
    const int ec = blockIdx.x;
    const int s = token_at[ec];
    ushort4* dst = reinterpret_cast<ushort4*>(disp + (size_t)ec * M_);
    if (s >= 0) {
        const float4 v = reinterpret_cast<const float4*>(h2 + (size_t)s * M_)[threadIdx.x];
        dst[threadIdx.x] = make_ushort4(f2bf(v.x), f2bf(v.y), f2bf(v.z), f2bf(v.w));
    } else {
        dst[threadIdx.x] = make_ushort4(0, 0, 0, 0);
    }
}

// Transpose+convert: in[e][R][Cc] f32 -> out[e][Cc][R] bf16.
__global__ __launch_bounds__(256) void transpose_bf16_kernel(const float* __restrict__ in,
                                                             ushort_t* __restrict__ outp,
                                                             int R, int Cc)
{
    __shared__ float tile[32][33];
    const int e = blockIdx.z;
    in   += (size_t)e * R * Cc;
    outp += (size_t)e * R * Cc;
    const int tx = threadIdx.x & 31, ty0 = threadIdx.x >> 5;
    const int c0 = blockIdx.x * 32, r0 = blockIdx.y * 32;
    #pragma unroll
    for (int i = 0; i < 4; ++i)
        tile[ty0 + 8*i][tx] = in[(size_t)(r0 + ty0 + 8*i) * Cc + c0 + tx];
    __syncthreads();
    #pragma unroll
    for (int i = 0; i < 4; ++i)
        outp[(size_t)(c0 + ty0 + 8*i) * R + r0 + tx] = f2bf(tile[tx][ty0 + 8*i]);
}

// ---------------------------------------------------------------------------
// bf16 MFMA GEMM (MoE FFN, post-router) — unchanged, verified.
// ---------------------------------------------------------------------------
template<int EPI>
__global__ __launch_bounds__(256) void gemm_mfma(
    const ushort_t* __restrict__ A, const ushort_t* __restrict__ Bt,
    const float* __restrict__ bias,
    const int* __restrict__ token_at, const float* __restrict__ gate_val,
    void* __restrict__ Cout, int N, int K,
    long strA, long strB, long strBias, long strC)
{
    const int e = blockIdx.z;
    A    += (size_t)e * (size_t)strA;
    Bt   += (size_t)e * (size_t)strB;
    bias += (size_t)e * (size_t)strBias;

    __shared__ ushort_t As[128 * 32];
    __shared__ ushort_t Bs[128 * 32];

    const int t  = threadIdx.x;
    const int l  = t & 63;
    const int wv = t >> 6;
    const int wm = (wv & 1) * 64, wn = (wv >> 1) * 64;
    const int fr = l & 15, fk = (l >> 4) * 8;
    const int m0 = blockIdx.y * 128, n0 = blockIdx.x * 128;

    const ushort_t* gA = A + (size_t)(m0 + (t >> 2)) * K + (t & 3) * 8;
    const ushort_t* gB = Bt + (size_t)(n0 + (t >> 2)) * K + (t & 3) * 8;
    ushort_t* lA = As + wv * 512;
    ushort_t* lB = Bs + wv * 512;

    f32x4 acc[4][4] = {};

    for (int k0 = 0; k0 < K; k0 += 32) {
        __syncthreads();
        gload_lds16(gA + k0, lA);
        gload_lds16(gA + k0 + (size_t)64 * K, lA + 2048);
        gload_lds16(gB + k0, lB);
        gload_lds16(gB + k0 + (size_t)64 * K, lB + 2048);
        __syncthreads();
        bf16x8 af[4], bfr[4];
        #pragma unroll
        for (int i = 0; i < 4; ++i)
            af[i] = *reinterpret_cast<const bf16x8*>(&As[(wm + i*16 + fr) * 32 + fk]);
        #pragma unroll
        for (int i = 0; i < 4; ++i)
            bfr[i] = *reinterpret_cast<const bf16x8*>(&Bs[(wn + i*16 + fr) * 32 + fk]);
        #pragma unroll
        for (int mi = 0; mi < 4; ++mi) {
            #pragma unroll
            for (int ni = 0; ni < 4; ++ni)
                acc[mi][ni] = __builtin_amdgcn_mfma_f32_16x16x32_bf16(
                    af[mi], bfr[ni], acc[mi][ni], 0, 0, 0);
        }
    }

    const int l4 = (l >> 4) * 4;
    if (EPI == 0) {
        ushort_t* Cc = (ushort_t*)Cout + (size_t)e * (size_t)strC;
        #pragma unroll
        for (int ni = 0; ni < 4; ++ni) {
            const int cl = n0 + wn + ni*16 + fr;
            const float bb = bias[cl];
            #pragma unroll
            for (int mi = 0; mi < 4; ++mi) {
                #pragma unroll
                for (int i = 0; i < 4; ++i) {
                    const int rr = m0 + wm + mi*16 + l4 + i;
                    Cc[(size_t)rr * N + cl] = f2bf(gelu_exact(acc[mi][ni][i] + bb));
                }
            }
        }
    } else {
        float* Co = (float*)Cout;
        const int* ta = token_at + e * C_;
        #pragma unroll
        for (int mi = 0; mi < 4; ++mi) {
            #pragma unroll
            for (int i = 0; i < 4; ++i) {
                const int rr = m0 + wm + mi*16 + l4 + i;
                const int s = ta[rr];
                if (s >= 0) {
                    const float gvl = gate_val[s];
                    #pragma unroll
                    for (int ni = 0; ni < 4; ++ni) {
                        const int cl = n0 + wn + ni*16 + fr;
                        Co[(size_t)s * N + cl] += gvl * (acc[mi][ni][i] + bias[cl]);
                    }
                }
            }
        }
    }
}

// ---------------------------------------------------------------------------
extern "C" void kernel_launch(void* const* d_in, const int* in_sizes, int n_in,
                              void* d_out, int out_size, void* d_ws, size_t ws_size,
                              hipStream_t stream)
{
    const float* x    = (const float*)d_in[0];
    const float* ln1g = (const float*)d_in[1];
    const float* ln1b = (const float*)d_in[2];
    const float* Wqkv = (const float*)d_in[3];
    const float* bqkv = (const float*)d_in[4];
    const float* Wout = (const float*)d_in[5];
    const float* bout = (const float*)d_in[6];
    const float* ln2g = (const float*)d_in[7];
    const float* ln2b = (const float*)d_in[8];
    const float* wg   = (const float*)d_in[9];
    const float* w1   = (const float*)d_in[10];
    const float* b1   = (const float*)d_in[11];
    const float* w2   = (const float*)d_in[12];
    const float* b2   = (const float*)d_in[13];
    float* out = (float*)d_out;

    // Workspace layout (MiB offsets), lifetime-scheduled. Peak ~176 MiB.
    //  [0,32)    ahi/alo (ph1) -> ohi/olo (ph3) -> buf_h (ph4)
    //  [32,128)  buf_qkv (ph1-2) -> w1t/w2t [32,96) + dispb [96,112) (ph4)
    //  [112,176) h1b (ph4)
    //  [128,160) buf_o (ph2-3, inside h1b region, disjoint lifetime)
    //  [160,172) wqh/wql (ph1)
    //  [172,176) woh/wol (ph1-3)
    //  [176,+)   router smalls
    char* ws = (char*)d_ws;
    ushort_t* ahi     = (ushort_t*)ws;
    ushort_t* alo     = (ushort_t*)(ws + ((size_t)16  << 20));
    ushort_t* ohi     = (ushort_t*)ws;
    ushort_t* olo     = (ushort_t*)(ws + ((size_t)16  << 20));
    float*    buf_h   = (float*)ws;
    float*    buf_qkv = (float*)(ws + ((size_t)32  << 20));
    float*    buf_o   = (float*)(ws + ((size_t)128 << 20));
    ushort_t* w1t     = (ushort_t*)(ws + ((size_t)32  << 20));
    ushort_t* w2t     = (ushort_t*)(ws + ((size_t)32  << 20));
    ushort_t* dispb   = (ushort_t*)(ws + ((size_t)96  << 20));
    ushort_t* h1b     = (ushort_t*)(ws + ((size_t)112 << 20));
    ushort_t* wqh     = (ushort_t*)(ws + ((size_t)160 << 20));
    ushort_t* wql     = (ushort_t*)(ws + ((size_t)166 << 20));
    ushort_t* woh     = (ushort_t*)(ws + ((size_t)172 << 20));
    ushort_t* wol     = (ushort_t*)(ws + ((size_t)174 << 20));
    float*    buf_gtop= (float*)(ws + ((size_t)176 << 20));
    float*    buf_gv  = buf_gtop + S_;
    int*      buf_idx = (int*)(buf_gv + S_);
    int*      buf_ta  = buf_idx + S_;

    // --- pre-router path (f32-grade via bf16x3 MFMA) ---
    split_kernel<<<(3*M_*M_/4 + 255)/256, 256, 0, stream>>>(Wqkv, wqh, wql, 3*M_*M_/4);
    split_kernel<<<(M_*M_/4 + 255)/256, 256, 0, stream>>>(Wout, woh, wol, M_*M_/4);
    ln_split_kernel<<<S_, 256, 0, stream>>>(x, ln1g, ln1b, ahi, alo);
    gemm_bf16x3<0><<<dim3(3*M_/128, S_/128, 1), 256, 0, stream>>>(
        ahi, alo, wqh, wql, bqkv, nullptr, buf_qkv, 3*M_, M_);
    attn_mfma_kernel<<<dim3(T_/64, H_, B_), 256, 0, stream>>>(buf_qkv, buf_o);
    split_kernel<<<(S_*M_/4 + 255)/256, 256, 0, stream>>>(buf_o, ohi, olo, S_*M_/4);
    gemm_bf16x3<1><<<dim3(M_/128, S_/128, 1), 256, 0, stream>>>(
        ohi, olo, woh, wol, bout, x, out, M_, M_);

    // --- router (exact f32) ---
    ln_kernel<<<S_, 256, 0, stream>>>(out, ln2g, ln2b, buf_h);
    gate_kernel<<<S_, 256, 0, stream>>>(buf_h, wg, buf_idx, buf_gtop);
    scan_kernel<<<1, 1024, 0, stream>>>(buf_idx, buf_gtop, buf_gv, buf_ta);
    dispatch_bf16_kernel<<<E_*C_, 256, 0, stream>>>(buf_h, buf_ta, dispb);

    // --- MoE FFN (bf16 MFMA, post-router) ---
    transpose_bf16_kernel<<<dim3(F_/32, M_/32, E_), 256, 0, stream>>>(w1, w1t, M_, F_);
    gemm_mfma<0><<<dim3(F_/128, C_/128, E_), 256, 0, stream>>>(
        dispb, w1t, b1, nullptr, nullptr, h1b, F_, M_,
        (long)C_*M_, (long)F_*M_, (long)F_, (long)C_*F_);
    transpose_bf16_kernel<<<dim3(M_/32, F_/32, E_), 256, 0, stream>>>(w2, w2t, F_, M_);
    gemm_mfma<1><<<dim3(M_/128, C_/128, E_), 256, 0, stream>>>(
        h1b, w2t, b2, buf_ta, buf_gv, out, M_, F_,
        (long)C_*F_, (long)M_*F_, (long)M_, 0);
}

// Round 6
// 1155.106 us; speedup vs baseline: 3.2622x; 1.0826x over previous
//
#include <hip/hip_runtime.h>
#include <hip/hip_bf16.h>
#include <math.h>

#define B_ 4
#define T_ 2048
#define M_ 1024
#define H_ 16
#define E_ 8
#define S_ (B_*T_)      // 8192
#define C_ (S_/E_)      // 1024
#define D_ (M_/H_)      // 64
#define F_ (4*M_)       // 4096

typedef unsigned short ushort_t;
typedef __attribute__((ext_vector_type(8))) short bf16x8;
typedef __attribute__((ext_vector_type(4))) float f32x4;

__device__ __forceinline__ float gelu_exact(float x) {
    return 0.5f * x * (1.0f + erff(x * 0.70710678118654752440f));
}

__device__ __forceinline__ unsigned short f2bf(float f) {
    unsigned int u = __float_as_uint(f);
    u = (u + 0x7FFFu + ((u >> 16) & 1u)) >> 16;   // RNE
    return (unsigned short)u;
}

__device__ __forceinline__ float bf2f(unsigned short h) {
    return __uint_as_float(((unsigned)h) << 16);
}

__device__ __forceinline__ void gload_lds16(const void* g, void* l) {
    __builtin_amdgcn_global_load_lds(
        (const __attribute__((address_space(1))) unsigned int*)g,
        (__attribute__((address_space(3))) unsigned int*)l,
        16, 0, 0);
}

__device__ __forceinline__ void lgkm0() {
    asm volatile("s_waitcnt lgkmcnt(0)" ::: "memory");
}

// ---------------------------------------------------------------------------
// LayerNorm (f32 out).
// ---------------------------------------------------------------------------
__global__ __launch_bounds__(256) void ln_kernel(const float* __restrict__ x,
                                                 const float* __restrict__ g,
                                                 const float* __restrict__ bta,
                                                 float* __restrict__ out)
{
    const int row = blockIdx.x;
    const int tid = threadIdx.x;
    const float4 v = reinterpret_cast<const float4*>(x + (size_t)row * M_)[tid];
    float s = v.x + v.y + v.z + v.w;
    __shared__ float red[4];
    #pragma unroll
    for (int off = 32; off > 0; off >>= 1) s += __shfl_down(s, off);
    if ((tid & 63) == 0) red[tid >> 6] = s;
    __syncthreads();
    const float mu = (red[0] + red[1] + red[2] + red[3]) * (1.0f / (float)M_);
    __syncthreads();
    float4 d;
    d.x = v.x - mu; d.y = v.y - mu; d.z = v.z - mu; d.w = v.w - mu;
    float q = d.x*d.x + d.y*d.y + d.z*d.z + d.w*d.w;
    #pragma unroll
    for (int off = 32; off > 0; off >>= 1) q += __shfl_down(q, off);
    if ((tid & 63) == 0) red[tid >> 6] = q;
    __syncthreads();
    const float var  = (red[0] + red[1] + red[2] + red[3]) * (1.0f / (float)M_);
    const float rstd = 1.0f / sqrtf(var + 1e-5f);
    const float4 gv = reinterpret_cast<const float4*>(g)[tid];
    const float4 bv = reinterpret_cast<const float4*>(bta)[tid];
    float4 o;
    o.x = d.x * rstd * gv.x + bv.x;
    o.y = d.y * rstd * gv.y + bv.y;
    o.z = d.z * rstd * gv.z + bv.z;
    o.w = d.w * rstd * gv.w + bv.w;
    reinterpret_cast<float4*>(out + (size_t)row * M_)[tid] = o;
}

// LayerNorm fused with hi/lo bf16 split output.
__global__ __launch_bounds__(256) void ln_split_kernel(const float* __restrict__ x,
                                                       const float* __restrict__ g,
                                                       const float* __restrict__ bta,
                                                       ushort_t* __restrict__ hi,
                                                       ushort_t* __restrict__ lo)
{
    const int row = blockIdx.x;
    const int tid = threadIdx.x;
    const float4 v = reinterpret_cast<const float4*>(x + (size_t)row * M_)[tid];
    float s = v.x + v.y + v.z + v.w;
    __shared__ float red[4];
    #pragma unroll
    for (int off = 32; off > 0; off >>= 1) s += __shfl_down(s, off);
    if ((tid & 63) == 0) red[tid >> 6] = s;
    __syncthreads();
    const float mu = (red[0] + red[1] + red[2] + red[3]) * (1.0f / (float)M_);
    __syncthreads();
    float4 d;
    d.x = v.x - mu; d.y = v.y - mu; d.z = v.z - mu; d.w = v.w - mu;
    float q = d.x*d.x + d.y*d.y + d.z*d.z + d.w*d.w;
    #pragma unroll
    for (int off = 32; off > 0; off >>= 1) q += __shfl_down(q, off);
    if ((tid & 63) == 0) red[tid >> 6] = q;
    __syncthreads();
    const float var  = (red[0] + red[1] + red[2] + red[3]) * (1.0f / (float)M_);
    const float rstd = 1.0f / sqrtf(var + 1e-5f);
    const float4 gv = reinterpret_cast<const float4*>(g)[tid];
    const float4 bv = reinterpret_cast<const float4*>(bta)[tid];
    float o[4];
    o[0] = d.x * rstd * gv.x + bv.x;
    o[1] = d.y * rstd * gv.y + bv.y;
    o[2] = d.z * rstd * gv.z + bv.z;
    o[3] = d.w * rstd * gv.w + bv.w;
    ushort4 hh, ll;
    hh.x = f2bf(o[0]); ll.x = f2bf(o[0] - bf2f(hh.x));
    hh.y = f2bf(o[1]); ll.y = f2bf(o[1] - bf2f(hh.y));
    hh.z = f2bf(o[2]); ll.z = f2bf(o[2] - bf2f(hh.z));
    hh.w = f2bf(o[3]); ll.w = f2bf(o[3] - bf2f(hh.w));
    reinterpret_cast<ushort4*>(hi + (size_t)row * M_)[tid] = hh;
    reinterpret_cast<ushort4*>(lo + (size_t)row * M_)[tid] = ll;
}

// Elementwise f32 -> hi/lo bf16 split (weights).
__global__ __launch_bounds__(256) void split_kernel(const float* __restrict__ in,
                                                    ushort_t* __restrict__ hi,
                                                    ushort_t* __restrict__ lo,
                                                    int n4)
{
    const int i = blockIdx.x * 256 + threadIdx.x;
    if (i >= n4) return;
    const float4 v = reinterpret_cast<const float4*>(in)[i];
    ushort4 hh, ll;
    hh.x = f2bf(v.x); ll.x = f2bf(v.x - bf2f(hh.x));
    hh.y = f2bf(v.y); ll.y = f2bf(v.y - bf2f(hh.y));
    hh.z = f2bf(v.z); ll.z = f2bf(v.z - bf2f(hh.z));
    hh.w = f2bf(v.w); ll.w = f2bf(v.w - bf2f(hh.w));
    reinterpret_cast<ushort4*>(hi)[i] = hh;
    reinterpret_cast<ushort4*>(lo)[i] = ll;
}

// V^T pre-transpose: qkv hi/lo [s][3M] (V slice) -> vt hi/lo [(b*H+h)*64+d][T].
__global__ __launch_bounds__(256) void vtrans_kernel(const ushort_t* __restrict__ qkvh,
                                                     const ushort_t* __restrict__ qkvl,
                                                     ushort_t* __restrict__ vth,
                                                     ushort_t* __restrict__ vtl)
{
    __shared__ ushort_t tile[64][72];
    const int t0 = blockIdx.x * 64, h = blockIdx.y, b = blockIdx.z;
    const int tid = threadIdx.x;
    const int tr = tid & 63, dc = (tid >> 6) * 16;
    const size_t src = ((size_t)(b*T_ + t0 + tr)) * (3*M_) + 2*M_ + h*64 + dc;
    const int dr = tid & 63, tc = (tid >> 6) * 16;
    const size_t dst = ((size_t)((b*H_ + h)*64 + dr)) * T_ + t0 + tc;

    #pragma unroll
    for (int pass = 0; pass < 2; ++pass) {
        const ushort_t* in = pass ? qkvl : qkvh;
        ushort_t* outp     = pass ? vtl  : vth;
        *reinterpret_cast<bf16x8*>(&tile[tr][dc])     = *reinterpret_cast<const bf16x8*>(in + src);
        *reinterpret_cast<bf16x8*>(&tile[tr][dc + 8]) = *reinterpret_cast<const bf16x8*>(in + src + 8);
        __syncthreads();
        bf16x8 o0, o1;
        #pragma unroll
        for (int j = 0; j < 8; ++j) {
            o0[j] = (short)tile[tc + j][dr];
            o1[j] = (short)tile[tc + 8 + j][dr];
        }
        *reinterpret_cast<bf16x8*>(outp + dst)     = o0;
        *reinterpret_cast<bf16x8*>(outp + dst + 8) = o1;
        __syncthreads();
    }
}

// ---------------------------------------------------------------------------
// bf16x3 MFMA GEMM (f32-grade, pre-router). m97 structure, 4 LDS buffers.
// EPI 1: f32 out = acc + bias + res.   EPI 2: hi/lo bf16 out = split(acc+bias).
// ---------------------------------------------------------------------------
template<int EPI>
__global__ __launch_bounds__(256) void gemm_bf16x3(
    const ushort_t* __restrict__ Ahi, const ushort_t* __restrict__ Alo,
    const ushort_t* __restrict__ Bhi, const ushort_t* __restrict__ Blo,
    const float* __restrict__ bias, const float* __restrict__ res,
    void* __restrict__ C0, ushort_t* __restrict__ C1, int N, int K)
{
    __shared__ ushort_t AsH[128*32], AsL[128*32];
    __shared__ ushort_t BsH[128*32], BsL[128*32];

    const int t  = threadIdx.x;
    const int l  = t & 63;
    const int wv = t >> 6;
    const int wm = (wv & 1) * 64, wn = (wv >> 1) * 64;
    const int fr = l & 15, fk = (l >> 4) * 8;
    const int m0 = blockIdx.y * 128, n0 = blockIdx.x * 128;

    const size_t arow = (size_t)(m0 + (t >> 2)) * K + (t & 3) * 8;
    const size_t brow = (size_t)(n0 + (t >> 2)) * K + (t & 3) * 8;
    ushort_t* lAH = AsH + wv * 512;
    ushort_t* lAL = AsL + wv * 512;
    ushort_t* lBH = BsH + wv * 512;
    ushort_t* lBL = BsL + wv * 512;

    f32x4 acc[4][4] = {};

    for (int k0 = 0; k0 < K; k0 += 32) {
        __syncthreads();
        gload_lds16(Ahi + arow + k0, lAH);
        gload_lds16(Ahi + arow + k0 + (size_t)64 * K, lAH + 2048);
        gload_lds16(Alo + arow + k0, lAL);
        gload_lds16(Alo + arow + k0 + (size_t)64 * K, lAL + 2048);
        gload_lds16(Bhi + brow + k0, lBH);
        gload_lds16(Bhi + brow + k0 + (size_t)64 * K, lBH + 2048);
        gload_lds16(Blo + brow + k0, lBL);
        gload_lds16(Blo + brow + k0 + (size_t)64 * K, lBL + 2048);
        __syncthreads();
        bf16x8 ah[4], al[4], bh[4], bl[4];
        #pragma unroll
        for (int i = 0; i < 4; ++i) {
            ah[i] = *reinterpret_cast<const bf16x8*>(&AsH[(wm + i*16 + fr) * 32 + fk]);
            al[i] = *reinterpret_cast<const bf16x8*>(&AsL[(wm + i*16 + fr) * 32 + fk]);
            bh[i] = *reinterpret_cast<const bf16x8*>(&BsH[(wn + i*16 + fr) * 32 + fk]);
            bl[i] = *reinterpret_cast<const bf16x8*>(&BsL[(wn + i*16 + fr) * 32 + fk]);
        }
        #pragma unroll
        for (int mi = 0; mi < 4; ++mi) {
            #pragma unroll
            for (int ni = 0; ni < 4; ++ni) {
                acc[mi][ni] = __builtin_amdgcn_mfma_f32_16x16x32_bf16(ah[mi], bh[ni], acc[mi][ni], 0, 0, 0);
                acc[mi][ni] = __builtin_amdgcn_mfma_f32_16x16x32_bf16(al[mi], bh[ni], acc[mi][ni], 0, 0, 0);
                acc[mi][ni] = __builtin_amdgcn_mfma_f32_16x16x32_bf16(ah[mi], bl[ni], acc[mi][ni], 0, 0, 0);
            }
        }
    }

    // C/D: col = lane&15, row = (lane>>4)*4 + reg
    const int l4 = (l >> 4) * 4;
    #pragma unroll
    for (int mi = 0; mi < 4; ++mi) {
        #pragma unroll
        for (int i = 0; i < 4; ++i) {
            const int row = m0 + wm + mi*16 + l4 + i;
            #pragma unroll
            for (int ni = 0; ni < 4; ++ni) {
                const int col = n0 + wn + ni*16 + fr;
                float v = acc[mi][ni][i] + bias[col];
                if (EPI == 1) {
                    v += res[(size_t)row * N + col];
                    ((float*)C0)[(size_t)row * N + col] = v;
                } else {
                    const ushort_t hb = f2bf(v);
                    ((ushort_t*)C0)[(size_t)row * N + col] = hb;
                    C1[(size_t)row * N + col] = f2bf(v - bf2f(hb));
                }
            }
        }
    }
}

// ---------------------------------------------------------------------------
// bf16x3 MFMA flash attention. K/V^T pre-split in global; staged via
// global_load_lds with pre-swizzled per-lane source (linear LDS dest receives
// the XOR-swizzled layout: LDS[row][c'] = G[row][c' ^ ((row&7)<<4)]).
// P through per-wave LDS (verified layout). Epilogue emits hi/lo bf16.
// ---------------------------------------------------------------------------
__global__ __launch_bounds__(256) void attn_mfma_kernel(
    const ushort_t* __restrict__ qkvh, const ushort_t* __restrict__ qkvl,
    const ushort_t* __restrict__ vth,  const ushort_t* __restrict__ vtl,
    ushort_t* __restrict__ ohi, ushort_t* __restrict__ olo)
{
    const int qt = blockIdx.x, h = blockIdx.y, b = blockIdx.z;
    const int q0 = qt * 64;
    const int t = threadIdx.x;
    const int w = t >> 6, l = t & 63;
    const int r = l & 15, g = l >> 4;
    const size_t rowbase = (size_t)b * T_;
    const int hoff = h * D_;

    __shared__ ushort_t Khi[64*64], Klo[64*64];   // [kv][64] swizzled
    __shared__ ushort_t Vhi[64*64], Vlo[64*64];   // V^T [d][64 kv] swizzled
    __shared__ ushort_t Ph[4*16*72], Pl[4*16*72];

    // Q fragments (A-frag: row = l&15, k = 32ks + 8g + j)
    bf16x8 qh[2], ql[2];
    {
        const size_t qrow = (rowbase + q0 + 16*w + r) * (size_t)(3*M_) + hoff;
        #pragma unroll
        for (int ks = 0; ks < 2; ++ks) {
            qh[ks] = *reinterpret_cast<const bf16x8*>(qkvh + qrow + 32*ks + 8*g);
            ql[ks] = *reinterpret_cast<const bf16x8*>(qkvl + qrow + 32*ks + 8*g);
        }
    }

    // gload staging: lane covers LDS row = w*8 + c*32 + (l>>3), bytes (l&7)*16;
    // row&7 = l>>3, so source col = ((l&7) ^ (l>>3)) * 8 elements (const/lane).
    const int srow = w*8 + (l >> 3);
    const int scol = ((l & 7) ^ (l >> 3)) * 8;
    const size_t ksrc0 = (rowbase + srow) * (size_t)(3*M_) + hoff + M_ + scol;
    const size_t vsrc0 = ((size_t)((b*H_ + h)*64 + srow)) * T_ + scol;
    const int lds0 = w * 512;                      // ushorts; +2048 for c=1

    f32x4 oa[4] = {};
    float mrow[4] = {-__builtin_inff(), -__builtin_inff(), -__builtin_inff(), -__builtin_inff()};
    float lrow[4] = {};

    for (int kt = 0; kt <= qt; ++kt) {
        __syncthreads();                           // prior tile's LDS reads done
        {
            const size_t kb = ksrc0 + (size_t)(kt*64) * (3*M_);
            const size_t vb = vsrc0 + kt*64;
            const size_t kstep = (size_t)32 * (3*M_);
            gload_lds16(qkvh + kb,         Khi + lds0);
            gload_lds16(qkvh + kb + kstep, Khi + lds0 + 2048);
            gload_lds16(qkvl + kb,         Klo + lds0);
            gload_lds16(qkvl + kb + kstep, Klo + lds0 + 2048);
            gload_lds16(vth + vb,           Vhi + lds0);
            gload_lds16(vth + vb + 32*T_,   Vhi + lds0 + 2048);
            gload_lds16(vtl + vb,           Vlo + lds0);
            gload_lds16(vtl + vb + 32*T_,   Vlo + lds0 + 2048);
        }
        __syncthreads();                           // drains vmcnt (gload done)

        // ---- QK^T: S[16 q][64 kv], bf16x3 ----
        f32x4 sa[4] = {};
        #pragma unroll
        for (int ks = 0; ks < 2; ++ks) {
            bf16x8 kh[4], kl[4];
            #pragma unroll
            for (int nf = 0; nf < 4; ++nf) {
                const int row = 16*nf + r;
                const unsigned boff = (unsigned)(row * 128)
                    + (((unsigned)(ks*64 + g*16)) ^ ((unsigned)((row & 7) << 4)));
                kh[nf] = *reinterpret_cast<const bf16x8*>((const char*)Khi + boff);
                kl[nf] = *reinterpret_cast<const bf16x8*>((const char*)Klo + boff);
            }
            #pragma unroll
            for (int nf = 0; nf < 4; ++nf) {
                sa[nf] = __builtin_amdgcn_mfma_f32_16x16x32_bf16(qh[ks], kh[nf], sa[nf], 0, 0, 0);
                sa[nf] = __builtin_amdgcn_mfma_f32_16x16x32_bf16(ql[ks], kh[nf], sa[nf], 0, 0, 0);
                sa[nf] = __builtin_amdgcn_mfma_f32_16x16x32_bf16(qh[ks], kl[nf], sa[nf], 0, 0, 0);
            }
        }

        // ---- scale + causal mask ----
        float sv[4][4];
        #pragma unroll
        for (int nf = 0; nf < 4; ++nf)
            #pragma unroll
            for (int i = 0; i < 4; ++i)
                sv[nf][i] = sa[nf][i] * 0.125f;
        if (kt == qt) {
            #pragma unroll
            for (int nf = 0; nf < 4; ++nf) {
                const int kvg = kt*64 + 16*nf + r;
                #pragma unroll
                for (int i = 0; i < 4; ++i) {
                    const int qg = q0 + 16*w + 4*g + i;
                    if (kvg > qg) sv[nf][i] = -3.0e38f;
                }
            }
        }

        // ---- online softmax ----
        float tmax[4];
        #pragma unroll
        for (int i = 0; i < 4; ++i)
            tmax[i] = fmaxf(fmaxf(sv[0][i], sv[1][i]), fmaxf(sv[2][i], sv[3][i]));
        #pragma unroll
        for (int off = 1; off < 16; off <<= 1)
            #pragma unroll
            for (int i = 0; i < 4; ++i)
                tmax[i] = fmaxf(tmax[i], __shfl_xor(tmax[i], off));
        float mnew[4], corr[4];
        #pragma unroll
        for (int i = 0; i < 4; ++i) {
            mnew[i] = fmaxf(mrow[i], tmax[i]);
            corr[i] = expf(mrow[i] - mnew[i]);
        }
        float p[4][4];
        float rsum[4] = {};
        #pragma unroll
        for (int nf = 0; nf < 4; ++nf)
            #pragma unroll
            for (int i = 0; i < 4; ++i) {
                p[nf][i] = expf(sv[nf][i] - mnew[i]);
                rsum[i] += p[nf][i];
            }
        #pragma unroll
        for (int off = 1; off < 16; off <<= 1)
            #pragma unroll
            for (int i = 0; i < 4; ++i)
                rsum[i] += __shfl_xor(rsum[i], off);
        #pragma unroll
        for (int i = 0; i < 4; ++i) {
            lrow[i] = lrow[i] * corr[i] + rsum[i];
            mrow[i] = mnew[i];
        }
        #pragma unroll
        for (int df = 0; df < 4; ++df)
            #pragma unroll
            for (int i = 0; i < 4; ++i)
                oa[df][i] *= corr[i];

        // ---- write P (per-wave [16 q][72 kv], hi/lo) ----
        #pragma unroll
        for (int nf = 0; nf < 4; ++nf) {
            const int kv = 16*nf + r;
            #pragma unroll
            for (int i = 0; i < 4; ++i) {
                const ushort_t phb = f2bf(p[nf][i]);
                Ph[(w*16 + 4*g + i) * 72 + kv] = phb;
                Pl[(w*16 + 4*g + i) * 72 + kv] = f2bf(p[nf][i] - bf2f(phb));
            }
        }
        lgkm0();

        // ---- PV: O += P·V, bf16x3 ----
        #pragma unroll
        for (int ks = 0; ks < 2; ++ks) {
            const bf16x8 ph = *reinterpret_cast<const bf16x8*>(&Ph[(w*16 + r) * 72 + 32*ks + 8*g]);
            const bf16x8 pl = *reinterpret_cast<const bf16x8*>(&Pl[(w*16 + r) * 72 + 32*ks + 8*g]);
            #pragma unroll
            for (int df = 0; df < 4; ++df) {
                const int vrow = 16*df + r;
                const unsigned voff = (unsigned)(vrow * 128)
                    + (((unsigned)(ks*64 + g*16)) ^ ((unsigned)((vrow & 7) << 4)));
                const bf16x8 vhf = *reinterpret_cast<const bf16x8*>((const char*)Vhi + voff);
                const bf16x8 vlf = *reinterpret_cast<const bf16x8*>((const char*)Vlo + voff);
                oa[df] = __builtin_amdgcn_mfma_f32_16x16x32_bf16(ph, vhf, oa[df], 0, 0, 0);
                oa[df] = __builtin_amdgcn_mfma_f32_16x16x32_bf16(pl, vhf, oa[df], 0, 0, 0);
                oa[df] = __builtin_amdgcn_mfma_f32_16x16x32_bf16(ph, vlf, oa[df], 0, 0, 0);
            }
        }
    }

    // ---- epilogue: hi/lo split of O / l ----
    #pragma unroll
    for (int i = 0; i < 4; ++i) {
        const float inv = 1.0f / lrow[i];
        const size_t row = (rowbase + q0 + 16*w + 4*g + i) * (size_t)M_ + hoff;
        #pragma unroll
        for (int df = 0; df < 4; ++df) {
            const float v = oa[df][i] * inv;
            const ushort_t hb = f2bf(v);
            ohi[row + 16*df + r] = hb;
            olo[row + 16*df + r] = f2bf(v - bf2f(hb));
        }
    }
}

// ---------------------------------------------------------------------------
// Router + deepspeed dispatch bookkeeping (exact, f32).
// ---------------------------------------------------------------------------
__global__ __launch_bounds__(256) void gate_kernel(const float* __restrict__ h2,
                                                   const float* __restrict__ wg,
                                                   int* __restrict__ gidx,
                                                   float* __restrict__ gtop)
{
    const int s = blockIdx.x;
    const int e = threadIdx.x >> 5;
    const int l = threadIdx.x & 31;
    const float* row = h2 + (size_t)s * M_;
    float acc = 0.0f;
    for (int m = l; m < M_; m += 32) acc = fmaf(row[m], wg[m * E_ + e], acc);
    #pragma unroll
    for (int off = 16; off > 0; off >>= 1) acc += __shfl_down(acc, off, 32);
    __shared__ float lg[E_];
    if (l == 0) lg[e] = acc;
    __syncthreads();
    if (threadIdx.x == 0) {
        float mx = lg[0]; int bi = 0;
        #pragma unroll
        for (int i = 1; i < E_; ++i) { if (lg[i] > mx) { mx = lg[i]; bi = i; } }
        float den = 0.0f;
        #pragma unroll
        for (int i = 0; i < E_; ++i) den += expf(lg[i] - mx);
        gidx[s] = bi;
        gtop[s] = 1.0f / den;
    }
}

__global__ __launch_bounds__(1024) void scan_kernel(const int* __restrict__ gidx,
                                                    const float* __restrict__ gtop,
                                                    float* __restrict__ gate_val,
                                                    int* __restrict__ token_at)
{
    __shared__ int hist[1024][E_];
    const int tid = threadIdx.x;
    for (int i = tid; i < E_ * C_; i += 1024) token_at[i] = -1;
    int my[8];
    #pragma unroll
    for (int t = 0; t < 8; ++t) my[t] = gidx[tid * 8 + t];
    #pragma unroll
    for (int e = 0; e < E_; ++e) {
        int c = 0;
        #pragma unroll
        for (int t = 0; t < 8; ++t) c += (my[t] == e) ? 1 : 0;
        hist[tid][e] = c;
    }
    __syncthreads();
    if (tid < E_) {
        int run = 0;
        for (int t = 0; t < 1024; ++t) {
            const int v = hist[t][tid];
            hist[t][tid] = run;
            run += v;
        }
    }
    __syncthreads();
    #pragma unroll
    for (int t = 0; t < 8; ++t) {
        const int s = tid * 8 + t;
        const int e = my[t];
        const int p = hist[tid][e];
        hist[tid][e] = p + 1;
        const bool keep = (p < C_);
        gate_val[s] = keep ? gtop[s] : 0.0f;
        if (keep) token_at[e * C_ + p] = s;
    }
}

__global__ __launch_bounds__(256) void dispatch_bf16_kernel(const float* __restrict__ h2,
                                                            const int* __restrict__ token_at,
                                                            ushort_t* __restrict__ disp)
{
    const int ec = blockIdx.x;
    const int s = token_at[ec];
    ushort4* dst = reinterpret_cast<ushort4*>(disp + (size_t)ec * M_);
    if (s >= 0) {
        const float4 v = reinterpret_cast<const float4*>(h2 + (size_t)s * M_)[threadIdx.x];
        dst[threadIdx.x] = make_ushort4(f2bf(v.x), f2bf(v.y), f2bf(v.z), f2bf(v.w));
    } else {
        dst[threadIdx.x] = make_ushort4(0, 0, 0, 0);
    }
}

// Transpose+convert: in[e][R][Cc] f32 -> out[e][Cc][R] bf16.
__global__ __launch_bounds__(256) void transpose_bf16_kernel(const float* __restrict__ in,
                                                             ushort_t* __restrict__ outp,
                                                             int R, int Cc)
{
    __shared__ float tile[32][33];
    const int e = blockIdx.z;
    in   += (size_t)e * R * Cc;
    outp += (size_t)e * R * Cc;
    const int tx = threadIdx.x & 31, ty0 = threadIdx.x >> 5;
    const int c0 = blockIdx.x * 32, r0 = blockIdx.y * 32;
    #pragma unroll
    for (int i = 0; i < 4; ++i)
        tile[ty0 + 8*i][tx] = in[(size_t)(r0 + ty0 + 8*i) * Cc + c0 + tx];
    __syncthreads();
    #pragma unroll
    for (int i = 0; i < 4; ++i)
        outp[(size_t)(c0 + ty0 + 8*i) * R + r0 + tx] = f2bf(tile[tx][ty0 + 8*i]);
}

// ---------------------------------------------------------------------------
// bf16 MFMA GEMM (MoE FFN, post-router) — unchanged, verified.
// ---------------------------------------------------------------------------
template<int EPI>
__global__ __launch_bounds__(256) void gemm_mfma(
    const ushort_t* __restrict__ A, const ushort_t* __restrict__ Bt,
    const float* __restrict__ bias,
    const int* __restrict__ token_at, const float* __restrict__ gate_val,
    void* __restrict__ Cout, int N, int K,
    long strA, long strB, long strBias, long strC)
{
    const int e = blockIdx.z;
    A    += (size_t)e * (size_t)strA;
    Bt   += (size_t)e * (size_t)strB;
    bias += (size_t)e * (size_t)strBias;

    __shared__ ushort_t As[128 * 32];
    __shared__ ushort_t Bs[128 * 32];

    const int t  = threadIdx.x;
    const int l  = t & 63;
    const int wv = t >> 6;
    const int wm = (wv & 1) * 64, wn = (wv >> 1) * 64;
    const int fr = l & 15, fk = (l >> 4) * 8;
    const int m0 = blockIdx.y * 128, n0 = blockIdx.x * 128;

    const ushort_t* gA = A + (size_t)(m0 + (t >> 2)) * K + (t & 3) * 8;
    const ushort_t* gB = Bt + (size_t)(n0 + (t >> 2)) * K + (t & 3) * 8;
    ushort_t* lA = As + wv * 512;
    ushort_t* lB = Bs + wv * 512;

    f32x4 acc[4][4] = {};

    for (int k0 = 0; k0 < K; k0 += 32) {
        __syncthreads();
        gload_lds16(gA + k0, lA);
        gload_lds16(gA + k0 + (size_t)64 * K, lA + 2048);
        gload_lds16(gB + k0, lB);
        gload_lds16(gB + k0 + (size_t)64 * K, lB + 2048);
        __syncthreads();
        bf16x8 af[4], bfr[4];
        #pragma unroll
        for (int i = 0; i < 4; ++i)
            af[i] = *reinterpret_cast<const bf16x8*>(&As[(wm + i*16 + fr) * 32 + fk]);
        #pragma unroll
        for (int i = 0; i < 4; ++i)
            bfr[i] = *reinterpret_cast<const bf16x8*>(&Bs[(wn + i*16 + fr) * 32 + fk]);
        #pragma unroll
        for (int mi = 0; mi < 4; ++mi) {
            #pragma unroll
            for (int ni = 0; ni < 4; ++ni)
                acc[mi][ni] = __builtin_amdgcn_mfma_f32_16x16x32_bf16(
                    af[mi], bfr[ni], acc[mi][ni], 0, 0, 0);
        }
    }

    const int l4 = (l >> 4) * 4;
    if (EPI == 0) {
        ushort_t* Cc = (ushort_t*)Cout + (size_t)e * (size_t)strC;
        #pragma unroll
        for (int ni = 0; ni < 4; ++ni) {
            const int cl = n0 + wn + ni*16 + fr;
            const float bb = bias[cl];
            #pragma unroll
            for (int mi = 0; mi < 4; ++mi) {
                #pragma unroll
                for (int i = 0; i < 4; ++i) {
                    const int rr = m0 + wm + mi*16 + l4 + i;
                    Cc[(size_t)rr * N + cl] = f2bf(gelu_exact(acc[mi][ni][i] + bb));
                }
            }
        }
    } else {
        float* Co = (float*)Cout;
        const int* ta = token_at + e * C_;
        #pragma unroll
        for (int mi = 0; mi < 4; ++mi) {
            #pragma unroll
            for (int i = 0; i < 4; ++i) {
                const int rr = m0 + wm + mi*16 + l4 + i;
                const int s = ta[rr];
                if (s >= 0) {
                    const float gvl = gate_val[s];
                    #pragma unroll
                    for (int ni = 0; ni < 4; ++ni) {
                        const int cl = n0 + wn + ni*16 + fr;
                        Co[(size_t)s * N + cl] += gvl * (acc[mi][ni][i] + bias[cl]);
                    }
                }
            }
        }
    }
}

// ---------------------------------------------------------------------------
extern "C" void kernel_launch(void* const* d_in, const int* in_sizes, int n_in,
                              void* d_out, int out_size, void* d_ws, size_t ws_size,
                              hipStream_t stream)
{
    const float* x    = (const float*)d_in[0];
    const float* ln1g = (const float*)d_in[1];
    const float* ln1b = (const float*)d_in[2];
    const float* Wqkv = (const float*)d_in[3];
    const float* bqkv = (const float*)d_in[4];
    const float* Wout = (const float*)d_in[5];
    const float* bout = (const float*)d_in[6];
    const float* ln2g = (const float*)d_in[7];
    const float* ln2b = (const float*)d_in[8];
    const float* wg   = (const float*)d_in[9];
    const float* w1   = (const float*)d_in[10];
    const float* b1   = (const float*)d_in[11];
    const float* w2   = (const float*)d_in[12];
    const float* b2   = (const float*)d_in[13];
    float* out = (float*)d_out;

    // Workspace (MiB offsets), lifetime-scheduled. Peak ~196 MiB.
    //  [0,16)+[16,32)  ahi/alo (ph1) -> buf_h f32 (router phase)
    //  [32,80)+[80,128) qkv hi/lo     -> w1t/w2t [32,96) + dispb [96,112) (MoE)
    //  [128,144)+[144,160) vt hi/lo   (wqh/wql borrow [128,140) during ph1)
    //  [160,176)+[176,192) ohi/olo    ; h1b [112,176) in MoE phase
    //  [192,194)+[194,196) woh/wol    ; router smalls [196,+)
    char* ws = (char*)d_ws;
    ushort_t* ahi   = (ushort_t*)ws;
    ushort_t* alo   = (ushort_t*)(ws + ((size_t)16  << 20));
    float*    buf_h = (float*)ws;
    ushort_t* qkvh  = (ushort_t*)(ws + ((size_t)32  << 20));
    ushort_t* qkvl  = (ushort_t*)(ws + ((size_t)80  << 20));
    ushort_t* vth   = (ushort_t*)(ws + ((size_t)128 << 20));
    ushort_t* vtl   = (ushort_t*)(ws + ((size_t)144 << 20));
    ushort_t* ohi   = (ushort_t*)(ws + ((size_t)160 << 20));
    ushort_t* olo   = (ushort_t*)(ws + ((size_t)176 << 20));
    ushort_t* wqh   = (ushort_t*)(ws + ((size_t)128 << 20));   // ph1 only
    ushort_t* wql   = (ushort_t*)(ws + ((size_t)134 << 20));   // ph1 only
    ushort_t* woh   = (ushort_t*)(ws + ((size_t)192 << 20));
    ushort_t* wol   = (ushort_t*)(ws + ((size_t)194 << 20));
    ushort_t* w1t   = (ushort_t*)(ws + ((size_t)32  << 20));
    ushort_t* w2t   = (ushort_t*)(ws + ((size_t)32  << 20));
    ushort_t* dispb = (ushort_t*)(ws + ((size_t)96  << 20));
    ushort_t* h1b   = (ushort_t*)(ws + ((size_t)112 << 20));
    float*    buf_gtop = (float*)(ws + ((size_t)196 << 20));
    float*    buf_gv   = buf_gtop + S_;
    int*      buf_idx  = (int*)(buf_gv + S_);
    int*      buf_ta   = buf_idx + S_;

    // --- pre-router path (f32-grade via bf16x3 MFMA) ---
    split_kernel<<<(3*M_*M_/4 + 255)/256, 256, 0, stream>>>(Wqkv, wqh, wql, 3*M_*M_/4);
    split_kernel<<<(M_*M_/4 + 255)/256, 256, 0, stream>>>(Wout, woh, wol, M_*M_/4);
    ln_split_kernel<<<S_, 256, 0, stream>>>(x, ln1g, ln1b, ahi, alo);
    gemm_bf16x3<2><<<dim3(3*M_/128, S_/128, 1), 256, 0, stream>>>(
        ahi, alo, wqh, wql, bqkv, nullptr, qkvh, qkvl, 3*M_, M_);
    vtrans_kernel<<<dim3(T_/64, H_, B_), 256, 0, stream>>>(qkvh, qkvl, vth, vtl);
    attn_mfma_kernel<<<dim3(T_/64, H_, B_), 256, 0, stream>>>(qkvh, qkvl, vth, vtl, ohi, olo);
    gemm_bf16x3<1><<<dim3(M_/128, S_/128, 1), 256, 0, stream>>>(
        ohi, olo, woh, wol, bout, x, out, nullptr, M_, M_);

    // --- router (exact f32) ---
    ln_kernel<<<S_, 256, 0, stream>>>(out, ln2g, ln2b, buf_h);
    gate_kernel<<<S_, 256, 0, stream>>>(buf_h, wg, buf_idx, buf_gtop);
    scan_kernel<<<1, 1024, 0, stream>>>(buf_idx, buf_gtop, buf_gv, buf_ta);
    dispatch_bf16_kernel<<<E_*C_, 256, 0, stream>>>(buf_h, buf_ta, dispb);

    // --- MoE FFN (bf16 MFMA, post-router) ---
    transpose_bf16_kernel<<<dim3(F_/32, M_/32, E_), 256, 0, stream>>>(w1, w1t, M_, F_);
    gemm_mfma<0><<<dim3(F_/128, C_/128, E_), 256, 0, stream>>>(
        dispb, w1t, b1, nullptr, nullptr, h1b, F_, M_,
        (long)C_*M_, (long)F_*M_, (long)F_, (long)C_*F_);
    transpose_bf16_kernel<<<dim3(M_/32, F_/32, E_), 256, 0, stream>>>(w2, w2t, F_, M_);
    gemm_mfma<1><<<dim3(M_/128, C_/128, E_), 256, 0, stream>>>(
        h1b, w2t, b2, buf_ta, buf_gv, out, M_, F_,
        (long)C_*F_, (long)M_*F_, (long)M_, 0);
}